// Round 3
// baseline (806.611 us; speedup 1.0000x reference)
//
#include <hip/hip_runtime.h>
#include <hip/hip_bf16.h>
#include <math.h>

#define NN 10000
#define EE 320000
#define DIM 256

__device__ __forceinline__ float bf2f(unsigned short u) {
  union { unsigned int ui; float f; } cv;
  cv.ui = ((unsigned int)u) << 16;
  return cv.f;
}

// one wave: decide {float inputs are f32 vs bf16} and {edge_index is int64 vs int32}
__global__ void k_detect(const unsigned int* __restrict__ xw, const int* __restrict__ ei,
                         int* __restrict__ flags) {
  int lane = threadIdx.x;
  int wild = 0;
  for (int t = 0; t < 16; ++t) {
    unsigned int w = xw[t * 64 + lane];
    unsigned int lo = w & 0xffffu;
    float f = bf2f((unsigned short)lo);
    float af = fabsf(f);
    if (lo != 0u && (af > 1e4f || af < 1e-30f)) wild++;
  }
  #pragma unroll
  for (int m = 1; m < 64; m <<= 1) wild += __shfl_xor(wild, m);
  int zeros = 0;
  for (int t = 0; t < 2; ++t) {
    if (ei[(t * 64 + lane) * 2 + 1] == 0) zeros++;
  }
  #pragma unroll
  for (int m = 1; m < 64; m <<= 1) zeros += __shfl_xor(zeros, m);
  if (lane == 0) {
    flags[0] = (wild > 100) ? 1 : 0;   // 1: floats are f32; 0: bf16
    flags[1] = (zeros > 100) ? 1 : 0;  // 1: indices are int64; 0: int32
  }
}

__global__ void k_cvt(const void* __restrict__ in, float* __restrict__ out, int n,
                      const int* __restrict__ flags) {
  int isf = flags[0];
  int i = blockIdx.x * blockDim.x + threadIdx.x;
  int stride = gridDim.x * blockDim.x;
  if (isf) {
    const float* p = (const float*)in;
    for (; i < n; i += stride) out[i] = p[i];
  } else {
    const unsigned short* p = (const unsigned short*)in;
    for (; i < n; i += stride) out[i] = bf2f(p[i]);
  }
}

struct PBatch { const void* src[20]; int off[21]; };

__global__ void k_cvt_params(PBatch b, float* __restrict__ out, const int* __restrict__ flags) {
  int isf = flags[0];
  int total = b.off[20];
  for (int i = blockIdx.x * blockDim.x + threadIdx.x; i < total; i += gridDim.x * blockDim.x) {
    int k = 0;
    while (i >= b.off[k + 1]) k++;
    int j = i - b.off[k];
    out[i] = isf ? ((const float*)b.src[k])[j] : bf2f(((const unsigned short*)b.src[k])[j]);
  }
}

__global__ void k_idx(const int* __restrict__ ei, int* __restrict__ s32, int* __restrict__ d32,
                      const int* __restrict__ flags) {
  int i64 = flags[1];
  for (int i = blockIdx.x * blockDim.x + threadIdx.x; i < EE; i += gridDim.x * blockDim.x) {
    if (i64) {
      s32[i] = ei[2 * i];
      d32[i] = ei[2 * (EE + i)];
    } else {
      s32[i] = ei[i];
      d32[i] = ei[EE + i];
    }
  }
}

__global__ void k_count(const int* __restrict__ dst, int* __restrict__ counts) {
  int i = blockIdx.x * blockDim.x + threadIdx.x;
  if (i < EE) atomicAdd(&counts[dst[i]], 1);
}

__global__ void k_scan(const int* __restrict__ counts, int* __restrict__ offsets,
                       int* __restrict__ cursor) {
  int lane = threadIdx.x;
  int run = 0;
  int nch = (NN + 63) / 64;
  for (int ch = 0; ch < nch; ++ch) {
    int i = ch * 64 + lane;
    int v = (i < NN) ? counts[i] : 0;
    int incl = v;
    #pragma unroll
    for (int off = 1; off < 64; off <<= 1) {
      int t = __shfl_up(incl, off);
      if (lane >= off) incl += t;
    }
    if (i < NN) { int ex = run + incl - v; offsets[i] = ex; cursor[i] = ex; }
    run += __shfl(incl, 63);
  }
  if (lane == 0) offsets[NN] = run;
}

__global__ void k_fill(const int* __restrict__ dst, int* __restrict__ cursor,
                       int* __restrict__ elist) {
  int i = blockIdx.x * blockDim.x + threadIdx.x;
  if (i < EE) {
    int p = atomicAdd(&cursor[dst[i]], 1);
    elist[p] = i;
  }
}

struct GemmArgs {
  const float* Hin;
  const float* W[4];
  const float* bias[4];
  float* Out[4];
};

// Out[which] = Hin @ W[which] + bias[which]; 16 rows x 256 cols per block.
__global__ __launch_bounds__(256) void k_gemm(GemmArgs a) {
  __shared__ float xs[16][DIM];
  int which = blockIdx.y;
  const float* W = a.W[which];
  const float* bias = a.bias[which];
  float* Out = a.Out[which];
  int row0 = blockIdx.x * 16;
  #pragma unroll
  for (int it = 0; it < 16; ++it) {
    int r = it, c = (int)threadIdx.x;
    int row = row0 + r;
    xs[r][c] = (row < NN) ? a.Hin[(size_t)row * DIM + c] : 0.f;
  }
  __syncthreads();
  int c0 = ((int)threadIdx.x & 63) * 4;
  int rg = (int)threadIdx.x >> 6;
  float acc[4][4] = {};
  for (int k = 0; k < DIM; k += 4) {
    float xv[4][4];
    #pragma unroll
    for (int rr = 0; rr < 4; ++rr) {
      float4 t = *reinterpret_cast<const float4*>(&xs[rg * 4 + rr][k]);
      xv[rr][0] = t.x; xv[rr][1] = t.y; xv[rr][2] = t.z; xv[rr][3] = t.w;
    }
    #pragma unroll
    for (int kk = 0; kk < 4; ++kk) {
      float4 w4 = *reinterpret_cast<const float4*>(&W[(size_t)(k + kk) * DIM + c0]);
      #pragma unroll
      for (int rr = 0; rr < 4; ++rr) {
        acc[rr][0] += xv[rr][kk] * w4.x;
        acc[rr][1] += xv[rr][kk] * w4.y;
        acc[rr][2] += xv[rr][kk] * w4.z;
        acc[rr][3] += xv[rr][kk] * w4.w;
      }
    }
  }
  float4 b4 = *reinterpret_cast<const float4*>(&bias[c0]);
  #pragma unroll
  for (int rr = 0; rr < 4; ++rr) {
    int row = row0 + rg * 4 + rr;
    if (row < NN) {
      float4 o;
      o.x = acc[rr][0] + b4.x; o.y = acc[rr][1] + b4.y;
      o.z = acc[rr][2] + b4.z; o.w = acc[rr][3] + b4.w;
      *reinterpret_cast<float4*>(&Out[(size_t)row * DIM + c0]) = o;
    }
  }
}

// one wave per node; 64 lanes = 8 heads x (8 lanes x 4 dims). online softmax.
__global__ __launch_bounds__(256) void k_attn(
    const float* __restrict__ Q, const float* __restrict__ K, const float* __restrict__ V,
    const float* __restrict__ We, const float* __restrict__ ewf,
    const int* __restrict__ src, const int* __restrict__ offsets,
    const int* __restrict__ elist, float* __restrict__ OutA) {
  int wid = (int)threadIdx.x >> 6, lane = (int)threadIdx.x & 63;
  int node = blockIdx.x * 4 + wid;
  if (node >= NN) return;
  int d0 = lane * 4;
  const float4 q4 = *reinterpret_cast<const float4*>(&Q[(size_t)node * DIM + d0]);
  const float4 we4 = *reinterpret_cast<const float4*>(&We[d0]);
  int beg = offsets[node], end = offsets[node + 1];
  float m = -INFINITY, l = 0.f, a0 = 0.f, a1 = 0.f, a2 = 0.f, a3 = 0.f;
  for (int p = beg; p < end; ++p) {
    int e = elist[p];
    int s = src[e];
    float w = ewf[e];
    const float4 k4 = *reinterpret_cast<const float4*>(&K[(size_t)s * DIM + d0]);
    const float4 v4 = *reinterpret_cast<const float4*>(&V[(size_t)s * DIM + d0]);
    float part = q4.x * (k4.x + w * we4.x) + q4.y * (k4.y + w * we4.y)
               + q4.z * (k4.z + w * we4.z) + q4.w * (k4.w + w * we4.w);
    part += __shfl_xor(part, 1);
    part += __shfl_xor(part, 2);
    part += __shfl_xor(part, 4);
    float alpha = part * 0.17677669529663687f; // 1/sqrt(32)
    float nm = fmaxf(m, alpha);
    float sc = __expf(m - nm);
    float pe = __expf(alpha - nm);
    l = l * sc + pe;
    a0 = a0 * sc + pe * (v4.x + w * we4.x);
    a1 = a1 * sc + pe * (v4.y + w * we4.y);
    a2 = a2 * sc + pe * (v4.z + w * we4.z);
    a3 = a3 * sc + pe * (v4.w + w * we4.w);
    m = nm;
  }
  float inv = 1.f / (l + 1e-16f);
  float4 o; o.x = a0 * inv; o.y = a1 * inv; o.z = a2 * inv; o.w = a3 * inv;
  *reinterpret_cast<float4*>(&OutA[(size_t)node * DIM + d0]) = o;
}

__global__ __launch_bounds__(256) void k_combine(
    const float* __restrict__ OA, const float* __restrict__ XR,
    const float* __restrict__ Wb,
    float* __restrict__ Hout, float* __restrict__ FinalOut) {
  int wid = (int)threadIdx.x >> 6, lane = (int)threadIdx.x & 63;
  int node = blockIdx.x * 4 + wid;
  if (node >= NN) return;
  int j0 = lane * 4;
  float4 o4 = *reinterpret_cast<const float4*>(&OA[(size_t)node * DIM + j0]);
  float4 x4 = *reinterpret_cast<const float4*>(&XR[(size_t)node * DIM + j0]);
  float4 wo = *reinterpret_cast<const float4*>(&Wb[j0]);
  float4 wx = *reinterpret_cast<const float4*>(&Wb[DIM + j0]);
  float4 wd = *reinterpret_cast<const float4*>(&Wb[2 * DIM + j0]);
  float part = o4.x * wo.x + o4.y * wo.y + o4.z * wo.z + o4.w * wo.w
             + x4.x * wx.x + x4.y * wx.y + x4.z * wx.z + x4.w * wx.w
             + (o4.x - x4.x) * wd.x + (o4.y - x4.y) * wd.y
             + (o4.z - x4.z) * wd.z + (o4.w - x4.w) * wd.w;
  #pragma unroll
  for (int msk = 1; msk < 64; msk <<= 1) part += __shfl_xor(part, msk);
  float beta = 1.f / (1.f + __expf(-part));
  float4 h;
  h.x = beta * x4.x + (1.f - beta) * o4.x;
  h.y = beta * x4.y + (1.f - beta) * o4.y;
  h.z = beta * x4.z + (1.f - beta) * o4.z;
  h.w = beta * x4.w + (1.f - beta) * o4.w;
  float* dst = FinalOut ? FinalOut : Hout;
  *reinterpret_cast<float4*>(&dst[(size_t)node * DIM + j0]) = h;
}

static inline size_t align256(size_t v) { return (v + 255) & ~(size_t)255; }

extern "C" void kernel_launch(void* const* d_in, const int* in_sizes, int n_in,
                              void* d_out, int out_size, void* d_ws, size_t ws_size,
                              hipStream_t stream) {
  const void* x = d_in[0];
  const int* eidx = (const int*)d_in[1];
  const void* ew = d_in[2];

  char* w = (char*)d_ws;
  size_t pos = 0;
  int* flags = (int*)(w + pos); pos = align256(pos + 2 * sizeof(int));
  const size_t fb = (size_t)NN * DIM * sizeof(float);
  float* H   = (float*)(w + pos); pos = align256(pos + fb);
  float* Qb  = (float*)(w + pos); pos = align256(pos + fb);
  float* Kb  = (float*)(w + pos); pos = align256(pos + fb);
  float* Vb  = (float*)(w + pos); pos = align256(pos + fb);
  float* XRb = (float*)(w + pos); pos = align256(pos + fb);
  float* OA  = (float*)(w + pos); pos = align256(pos + fb);
  float* ewf = (float*)(w + pos); pos = align256(pos + (size_t)EE * 4);
  int* s32   = (int*)(w + pos);   pos = align256(pos + (size_t)EE * 4);
  int* d32   = (int*)(w + pos);   pos = align256(pos + (size_t)EE * 4);
  int* counts  = (int*)(w + pos); pos = align256(pos + (size_t)NN * 4);
  int* offsets = (int*)(w + pos); pos = align256(pos + (size_t)(NN + 1) * 4);
  int* cursor  = (int*)(w + pos); pos = align256(pos + (size_t)NN * 4);
  int* elist   = (int*)(w + pos); pos = align256(pos + (size_t)EE * 4);
  float* Pf    = (float*)(w + pos);

  // params: d_in[3..22]
  PBatch pb;
  int off = 0;
  for (int i = 0; i < 20; ++i) {
    pb.src[i] = d_in[3 + i];
    pb.off[i] = off;
    off += in_sizes[3 + i];
  }
  pb.off[20] = off;

  k_detect<<<1, 64, 0, stream>>>((const unsigned int*)x, eidx, flags);
  k_idx<<<1250, 256, 0, stream>>>(eidx, s32, d32, flags);
  hipMemsetAsync(counts, 0, (size_t)NN * 4, stream);
  k_count<<<(EE + 255) / 256, 256, 0, stream>>>(d32, counts);
  k_scan<<<1, 64, 0, stream>>>(counts, offsets, cursor);
  k_fill<<<(EE + 255) / 256, 256, 0, stream>>>(d32, cursor, elist);
  k_cvt<<<2048, 256, 0, stream>>>(x, H, NN * DIM, flags);
  k_cvt<<<1250, 256, 0, stream>>>(ew, ewf, EE, flags);
  k_cvt_params<<<2064, 256, 0, stream>>>(pb, Pf, flags);

  // param f32 pointers
  const float* P[20];
  for (int i = 0; i < 20; ++i) P[i] = Pf + pb.off[i];

  for (int layer = 0; layer < 3; ++layer) {
    const float* const* pp = &P[(layer == 0 ? 0 : 1) * 10];
    GemmArgs ga;
    ga.Hin = H;
    ga.W[0] = pp[0]; ga.W[1] = pp[2]; ga.W[2] = pp[4]; ga.W[3] = pp[7];
    ga.bias[0] = pp[1]; ga.bias[1] = pp[3]; ga.bias[2] = pp[5]; ga.bias[3] = pp[8];
    ga.Out[0] = Qb; ga.Out[1] = Kb; ga.Out[2] = Vb; ga.Out[3] = XRb;
    k_gemm<<<dim3((NN + 15) / 16, 4), 256, 0, stream>>>(ga);
    k_attn<<<(NN + 3) / 4, 256, 0, stream>>>(Qb, Kb, Vb, pp[6], ewf, s32, offsets, elist, OA);
    k_combine<<<(NN + 3) / 4, 256, 0, stream>>>(OA, XRb, pp[9], H,
        (layer == 2) ? (float*)d_out : nullptr);
  }
}

// Round 4
// 621.232 us; speedup vs baseline: 1.2984x; 1.2984x over previous
//
#include <hip/hip_runtime.h>
#include <hip/hip_bf16.h>
#include <math.h>

#define NN 10000
#define EE 320000
#define DIM 256
#define SCANB 40  // ceil(NN/256)

__device__ __forceinline__ float bf2f(unsigned short u) {
  union { unsigned int ui; float f; } cv;
  cv.ui = ((unsigned int)u) << 16;
  return cv.f;
}

__device__ __forceinline__ void fma4(float4& a, float s, const float4& w) {
  a.x = fmaf(s, w.x, a.x); a.y = fmaf(s, w.y, a.y);
  a.z = fmaf(s, w.z, a.z); a.w = fmaf(s, w.w, a.w);
}

// one wave: decide {float inputs f32 vs bf16} and {edge_index int64 vs int32}
__global__ void k_detect(const unsigned int* __restrict__ xw, const int* __restrict__ ei,
                         int* __restrict__ flags) {
  int lane = threadIdx.x;
  int wild = 0;
  for (int t = 0; t < 16; ++t) {
    unsigned int w = xw[t * 64 + lane];
    unsigned int lo = w & 0xffffu;
    float f = bf2f((unsigned short)lo);
    float af = fabsf(f);
    if (lo != 0u && (af > 1e4f || af < 1e-30f)) wild++;
  }
  #pragma unroll
  for (int m = 1; m < 64; m <<= 1) wild += __shfl_xor(wild, m);
  int zeros = 0;
  for (int t = 0; t < 2; ++t) {
    if (ei[(t * 64 + lane) * 2 + 1] == 0) zeros++;
  }
  #pragma unroll
  for (int m = 1; m < 64; m <<= 1) zeros += __shfl_xor(zeros, m);
  if (lane == 0) {
    flags[0] = (wild > 100) ? 1 : 0;
    flags[1] = (zeros > 100) ? 1 : 0;
  }
}

__global__ void k_cvt(const void* __restrict__ in, float* __restrict__ out, int n,
                      const int* __restrict__ flags) {
  int isf = flags[0];
  int i = blockIdx.x * blockDim.x + threadIdx.x;
  int stride = gridDim.x * blockDim.x;
  if (isf) {
    const float* p = (const float*)in;
    for (; i < n; i += stride) out[i] = p[i];
  } else {
    const unsigned short* p = (const unsigned short*)in;
    for (; i < n; i += stride) out[i] = bf2f(p[i]);
  }
}

struct PBatch { const void* src[20]; int off[21]; };

__global__ void k_cvt_params(PBatch b, float* __restrict__ out, const int* __restrict__ flags) {
  int isf = flags[0];
  int total = b.off[20];
  for (int i = blockIdx.x * blockDim.x + threadIdx.x; i < total; i += gridDim.x * blockDim.x) {
    int k = 0;
    while (i >= b.off[k + 1]) k++;
    int j = i - b.off[k];
    out[i] = isf ? ((const float*)b.src[k])[j] : bf2f(((const unsigned short*)b.src[k])[j]);
  }
}

__global__ void k_idx_count(const int* __restrict__ ei, int* __restrict__ s32,
                            int* __restrict__ d32, int* __restrict__ counts,
                            const int* __restrict__ flags) {
  int i64 = flags[1];
  int i = blockIdx.x * blockDim.x + threadIdx.x;
  if (i < EE) {
    int s, d;
    if (i64) { s = ei[2 * i]; d = ei[2 * (EE + i)]; }
    else     { s = ei[i];     d = ei[EE + i]; }
    s32[i] = s; d32[i] = d;
    atomicAdd(&counts[d], 1);
  }
}

__global__ __launch_bounds__(256) void k_scan1(const int* __restrict__ counts,
                                               int* __restrict__ tmpoff,
                                               int* __restrict__ bsum) {
  __shared__ int s[256];
  int t = threadIdx.x;
  int i = blockIdx.x * 256 + t;
  int v = (i < NN) ? counts[i] : 0;
  s[t] = v;
  __syncthreads();
  for (int off = 1; off < 256; off <<= 1) {
    int x = (t >= off) ? s[t - off] : 0;
    __syncthreads();
    s[t] += x;
    __syncthreads();
  }
  if (i < NN) tmpoff[i] = s[t] - v;
  if (t == 255) bsum[blockIdx.x] = s[255];
}

__global__ void k_scan2(const int* __restrict__ bsum, int* __restrict__ bbase) {
  int lane = threadIdx.x;
  int v = (lane < SCANB) ? bsum[lane] : 0;
  int incl = v;
  #pragma unroll
  for (int off = 1; off < 64; off <<= 1) {
    int t = __shfl_up(incl, off);
    if (lane >= off) incl += t;
  }
  if (lane < SCANB) bbase[lane] = incl - v;
}

__global__ __launch_bounds__(256) void k_scan3(const int* __restrict__ tmpoff,
                                               const int* __restrict__ bbase,
                                               int* __restrict__ offsets,
                                               int* __restrict__ cursor) {
  int i = blockIdx.x * 256 + threadIdx.x;
  if (i < NN) {
    int o = tmpoff[i] + bbase[i >> 8];
    offsets[i] = o;
    cursor[i] = o;
  }
  if (i == 0) offsets[NN] = EE;
}

__global__ void k_fill_sort(const int* __restrict__ d32, const int* __restrict__ s32,
                            const float* __restrict__ ewf, int* __restrict__ cursor,
                            int* __restrict__ srcS, float* __restrict__ wS) {
  int i = blockIdx.x * blockDim.x + threadIdx.x;
  if (i < EE) {
    int p = atomicAdd(&cursor[d32[i]], 1);
    srcS[p] = s32[i];
    wS[p] = ewf[i];
  }
}

struct GemmArgs {
  const float* Hin;
  const float* W[4];
  const float* bias[4];
  float* Out[4];
};

// Out[which] = Hin @ W[which] + bias; tile 16 rows x 256 cols, W double-buffered in regs.
__global__ __launch_bounds__(256) void k_gemm(GemmArgs a) {
  __shared__ float xs[16][DIM];
  int which = blockIdx.y;
  const float* __restrict__ W = a.W[which];
  const float* __restrict__ bias = a.bias[which];
  float* __restrict__ Out = a.Out[which];
  int tid = (int)threadIdx.x;
  int row0 = blockIdx.x * 16;
  float4 z4 = make_float4(0.f, 0.f, 0.f, 0.f);
  #pragma unroll
  for (int it = 0; it < 4; ++it) {
    int idx = it * 1024 + tid * 4;
    int r = idx >> 8, c = idx & 255;
    int row = row0 + r;
    float4 v = (row < NN) ? *reinterpret_cast<const float4*>(&a.Hin[(size_t)row * DIM + c]) : z4;
    *reinterpret_cast<float4*>(&xs[r][c]) = v;
  }
  __syncthreads();
  int c0 = (tid & 63) * 4;
  int rg4 = (tid >> 6) * 4;
  const float* Wc = W + c0;
  float4 wc0 = *reinterpret_cast<const float4*>(Wc + 0);
  float4 wc1 = *reinterpret_cast<const float4*>(Wc + 256);
  float4 wc2 = *reinterpret_cast<const float4*>(Wc + 512);
  float4 wc3 = *reinterpret_cast<const float4*>(Wc + 768);
  float4 acc0 = z4, acc1 = z4, acc2 = z4, acc3 = z4;
  #pragma unroll 2
  for (int kg = 0; kg < 64; ++kg) {
    int kn = ((kg < 63) ? (kg + 1) : 63) << 10;  // next group's float offset
    const float* Wn = Wc + kn;
    float4 wn0 = *reinterpret_cast<const float4*>(Wn + 0);
    float4 wn1 = *reinterpret_cast<const float4*>(Wn + 256);
    float4 wn2 = *reinterpret_cast<const float4*>(Wn + 512);
    float4 wn3 = *reinterpret_cast<const float4*>(Wn + 768);
    float4 xv0 = *reinterpret_cast<const float4*>(&xs[rg4 + 0][kg * 4]);
    float4 xv1 = *reinterpret_cast<const float4*>(&xs[rg4 + 1][kg * 4]);
    float4 xv2 = *reinterpret_cast<const float4*>(&xs[rg4 + 2][kg * 4]);
    float4 xv3 = *reinterpret_cast<const float4*>(&xs[rg4 + 3][kg * 4]);
    fma4(acc0, xv0.x, wc0); fma4(acc0, xv0.y, wc1); fma4(acc0, xv0.z, wc2); fma4(acc0, xv0.w, wc3);
    fma4(acc1, xv1.x, wc0); fma4(acc1, xv1.y, wc1); fma4(acc1, xv1.z, wc2); fma4(acc1, xv1.w, wc3);
    fma4(acc2, xv2.x, wc0); fma4(acc2, xv2.y, wc1); fma4(acc2, xv2.z, wc2); fma4(acc2, xv2.w, wc3);
    fma4(acc3, xv3.x, wc0); fma4(acc3, xv3.y, wc1); fma4(acc3, xv3.z, wc2); fma4(acc3, xv3.w, wc3);
    wc0 = wn0; wc1 = wn1; wc2 = wn2; wc3 = wn3;
  }
  float4 b4 = *reinterpret_cast<const float4*>(&bias[c0]);
  float4 accs[4] = {acc0, acc1, acc2, acc3};
  #pragma unroll
  for (int rr = 0; rr < 4; ++rr) {
    int row = row0 + rg4 + rr;
    if (row < NN) {
      float4 o;
      o.x = accs[rr].x + b4.x; o.y = accs[rr].y + b4.y;
      o.z = accs[rr].z + b4.z; o.w = accs[rr].w + b4.w;
      *reinterpret_cast<float4*>(&Out[(size_t)row * DIM + c0]) = o;
    }
  }
}

#define ATT_STEP(KK, VV, WW) do { \
    float part = q4.x * fmaf(WW, we4.x, KK.x) + q4.y * fmaf(WW, we4.y, KK.y) \
               + q4.z * fmaf(WW, we4.z, KK.z) + q4.w * fmaf(WW, we4.w, KK.w); \
    part += __shfl_xor(part, 1); \
    part += __shfl_xor(part, 2); \
    part += __shfl_xor(part, 4); \
    float alpha = part * 0.17677669529663687f; \
    float nm = fmaxf(m, alpha); \
    float sc = __expf(m - nm); \
    float pe = __expf(alpha - nm); \
    l = l * sc + pe; \
    a0 = fmaf(a0, sc, pe * fmaf(WW, we4.x, VV.x)); \
    a1 = fmaf(a1, sc, pe * fmaf(WW, we4.y, VV.y)); \
    a2 = fmaf(a2, sc, pe * fmaf(WW, we4.z, VV.z)); \
    a3 = fmaf(a3, sc, pe * fmaf(WW, we4.w, VV.w)); \
    m = nm; \
  } while (0)

// one wave per node; 64 lanes = 8 heads x 8 lanes x 4 dims; fused gate/combine epilogue.
__global__ __launch_bounds__(256) void k_attn(
    const float* __restrict__ Q, const float* __restrict__ K, const float* __restrict__ V,
    const float* __restrict__ We, const float* __restrict__ XR,
    const float* __restrict__ Wb, const int* __restrict__ srcS,
    const float* __restrict__ wS, const int* __restrict__ offsets,
    float* __restrict__ Hout, float* __restrict__ FinalOut) {
  int wid = (int)threadIdx.x >> 6, lane = (int)threadIdx.x & 63;
  int node = blockIdx.x * 4 + wid;
  if (node >= NN) return;
  int d0 = lane * 4;
  const float4 q4 = *reinterpret_cast<const float4*>(&Q[(size_t)node * DIM + d0]);
  const float4 x4 = *reinterpret_cast<const float4*>(&XR[(size_t)node * DIM + d0]);
  const float4 we4 = *reinterpret_cast<const float4*>(&We[d0]);
  const float4 wo = *reinterpret_cast<const float4*>(&Wb[d0]);
  const float4 wx = *reinterpret_cast<const float4*>(&Wb[DIM + d0]);
  const float4 wd = *reinterpret_cast<const float4*>(&Wb[2 * DIM + d0]);
  int beg = offsets[node], end = offsets[node + 1];
  beg = __builtin_amdgcn_readfirstlane(beg);
  end = __builtin_amdgcn_readfirstlane(end);
  float m = -INFINITY, l = 0.f, a0 = 0.f, a1 = 0.f, a2 = 0.f, a3 = 0.f;
  if (end > beg) {
    int pLast = end - 1;
    int sA = srcS[beg];
    float wA = wS[beg];
    int p1 = (beg + 1 <= pLast) ? beg + 1 : pLast;
    int sB = srcS[p1];
    float wB = wS[p1];
    float4 kA = *reinterpret_cast<const float4*>(&K[(size_t)sA * DIM + d0]);
    float4 vA = *reinterpret_cast<const float4*>(&V[(size_t)sA * DIM + d0]);
    float4 kB = *reinterpret_cast<const float4*>(&K[(size_t)sB * DIM + d0]);
    float4 vB = *reinterpret_cast<const float4*>(&V[(size_t)sB * DIM + d0]);
    int p = beg;
    #pragma unroll 2
    for (; p + 2 < end; ++p) {
      int sN = srcS[p + 2];
      float wN = wS[p + 2];
      float4 kN = *reinterpret_cast<const float4*>(&K[(size_t)sN * DIM + d0]);
      float4 vN = *reinterpret_cast<const float4*>(&V[(size_t)sN * DIM + d0]);
      ATT_STEP(kA, vA, wA);
      kA = kB; vA = vB; wA = wB;
      kB = kN; vB = vN; wB = wN;
    }
    ATT_STEP(kA, vA, wA);
    if (p + 1 < end) ATT_STEP(kB, vB, wB);
  }
  float inv = 1.f / (l + 1e-16f);
  float o0 = a0 * inv, o1 = a1 * inv, o2 = a2 * inv, o3 = a3 * inv;
  // gate: beta = sigmoid([o, x, o-x] . Wbeta)
  float part = o0 * wo.x + o1 * wo.y + o2 * wo.z + o3 * wo.w
             + x4.x * wx.x + x4.y * wx.y + x4.z * wx.z + x4.w * wx.w
             + (o0 - x4.x) * wd.x + (o1 - x4.y) * wd.y
             + (o2 - x4.z) * wd.z + (o3 - x4.w) * wd.w;
  #pragma unroll
  for (int msk = 1; msk < 64; msk <<= 1) part += __shfl_xor(part, msk);
  float beta = 1.f / (1.f + __expf(-part));
  float4 h;
  h.x = beta * x4.x + (1.f - beta) * o0;
  h.y = beta * x4.y + (1.f - beta) * o1;
  h.z = beta * x4.z + (1.f - beta) * o2;
  h.w = beta * x4.w + (1.f - beta) * o3;
  float* dst = FinalOut ? FinalOut : Hout;
  *reinterpret_cast<float4*>(&dst[(size_t)node * DIM + d0]) = h;
}

static inline size_t align256(size_t v) { return (v + 255) & ~(size_t)255; }

extern "C" void kernel_launch(void* const* d_in, const int* in_sizes, int n_in,
                              void* d_out, int out_size, void* d_ws, size_t ws_size,
                              hipStream_t stream) {
  const void* x = d_in[0];
  const int* eidx = (const int*)d_in[1];
  const void* ew = d_in[2];

  char* w = (char*)d_ws;
  size_t pos = 0;
  int* flags = (int*)(w + pos); pos = align256(pos + 2 * sizeof(int));
  const size_t fb = (size_t)NN * DIM * sizeof(float);
  float* H   = (float*)(w + pos); pos = align256(pos + fb);
  float* Qb  = (float*)(w + pos); pos = align256(pos + fb);
  float* Kb  = (float*)(w + pos); pos = align256(pos + fb);
  float* Vb  = (float*)(w + pos); pos = align256(pos + fb);
  float* XRb = (float*)(w + pos); pos = align256(pos + fb);
  float* ewf = (float*)(w + pos); pos = align256(pos + (size_t)EE * 4);
  int* s32   = (int*)(w + pos);   pos = align256(pos + (size_t)EE * 4);
  int* d32   = (int*)(w + pos);   pos = align256(pos + (size_t)EE * 4);
  int* srcS  = (int*)(w + pos);   pos = align256(pos + (size_t)EE * 4);
  float* wS  = (float*)(w + pos); pos = align256(pos + (size_t)EE * 4);
  int* counts  = (int*)(w + pos); pos = align256(pos + (size_t)NN * 4);
  int* offsets = (int*)(w + pos); pos = align256(pos + (size_t)(NN + 1) * 4);
  int* cursor  = (int*)(w + pos); pos = align256(pos + (size_t)NN * 4);
  int* tmpoff  = (int*)(w + pos); pos = align256(pos + (size_t)NN * 4);
  int* bsum    = (int*)(w + pos); pos = align256(pos + 64 * 4);
  int* bbase   = (int*)(w + pos); pos = align256(pos + 64 * 4);
  float* Pf    = (float*)(w + pos);

  PBatch pb;
  int off = 0;
  for (int i = 0; i < 20; ++i) {
    pb.src[i] = d_in[3 + i];
    pb.off[i] = off;
    off += in_sizes[3 + i];
  }
  pb.off[20] = off;

  k_detect<<<1, 64, 0, stream>>>((const unsigned int*)x, eidx, flags);
  hipMemsetAsync(counts, 0, (size_t)NN * 4, stream);
  k_idx_count<<<(EE + 255) / 256, 256, 0, stream>>>(eidx, s32, d32, counts, flags);
  k_cvt<<<1250, 256, 0, stream>>>(ew, ewf, EE, flags);
  k_scan1<<<SCANB, 256, 0, stream>>>(counts, tmpoff, bsum);
  k_scan2<<<1, 64, 0, stream>>>(bsum, bbase);
  k_scan3<<<SCANB, 256, 0, stream>>>(tmpoff, bbase, offsets, cursor);
  k_fill_sort<<<(EE + 255) / 256, 256, 0, stream>>>(d32, s32, ewf, cursor, srcS, wS);
  k_cvt<<<2048, 256, 0, stream>>>(x, H, NN * DIM, flags);
  k_cvt_params<<<2064, 256, 0, stream>>>(pb, Pf, flags);

  const float* P[20];
  for (int i = 0; i < 20; ++i) P[i] = Pf + pb.off[i];

  for (int layer = 0; layer < 3; ++layer) {
    const float* const* pp = &P[(layer == 0 ? 0 : 1) * 10];
    GemmArgs ga;
    ga.Hin = H;
    ga.W[0] = pp[0]; ga.W[1] = pp[2]; ga.W[2] = pp[4]; ga.W[3] = pp[7];
    ga.bias[0] = pp[1]; ga.bias[1] = pp[3]; ga.bias[2] = pp[5]; ga.bias[3] = pp[8];
    ga.Out[0] = Qb; ga.Out[1] = Kb; ga.Out[2] = Vb; ga.Out[3] = XRb;
    k_gemm<<<dim3((NN + 15) / 16, 4), 256, 0, stream>>>(ga);
    k_attn<<<(NN + 3) / 4, 256, 0, stream>>>(Qb, Kb, Vb, pp[6], XRb, pp[9],
        srcS, wS, offsets, H, (layer == 2) ? (float*)d_out : nullptr);
  }
}

// Round 5
// 507.806 us; speedup vs baseline: 1.5884x; 1.2234x over previous
//
#include <hip/hip_runtime.h>
#include <hip/hip_bf16.h>
#include <math.h>

#define NN 10000
#define EE 320000
#define DIM 256
#define NROWS 10016   // NN padded to 32
#define SCANB 40      // ceil(NN/256)

typedef __attribute__((ext_vector_type(8))) short s16x8;
typedef __attribute__((ext_vector_type(4))) float f32x4;

__device__ __forceinline__ float bf2f(unsigned short u) {
  union { unsigned int ui; float f; } cv;
  cv.ui = ((unsigned int)u) << 16;
  return cv.f;
}

__device__ __forceinline__ unsigned short f2bf(float f) {
  union { float f; unsigned int u; } cv; cv.f = f;
  unsigned int u = cv.u;
  u += 0x7fffu + ((u >> 16) & 1u);
  return (unsigned short)(u >> 16);
}

// split f32 into hi+lo bf16 (hi = rne(v), lo = rne(v - hi))
__device__ __forceinline__ void split2(float v, unsigned short& hi, unsigned short& lo) {
  hi = f2bf(v);
  lo = f2bf(v - bf2f(hi));
}

// one wave: decide {float inputs f32 vs bf16} and {edge_index int64 vs int32}
__global__ void k_detect(const unsigned int* __restrict__ xw, const int* __restrict__ ei,
                         int* __restrict__ flags) {
  int lane = threadIdx.x;
  int wild = 0;
  for (int t = 0; t < 16; ++t) {
    unsigned int w = xw[t * 64 + lane];
    unsigned int lo = w & 0xffffu;
    float f = bf2f((unsigned short)lo);
    float af = fabsf(f);
    if (lo != 0u && (af > 1e4f || af < 1e-30f)) wild++;
  }
  #pragma unroll
  for (int m = 1; m < 64; m <<= 1) wild += __shfl_xor(wild, m);
  int zeros = 0;
  for (int t = 0; t < 2; ++t) {
    if (ei[(t * 64 + lane) * 2 + 1] == 0) zeros++;
  }
  #pragma unroll
  for (int m = 1; m < 64; m <<= 1) zeros += __shfl_xor(zeros, m);
  if (lane == 0) {
    flags[0] = (wild > 100) ? 1 : 0;
    flags[1] = (zeros > 100) ? 1 : 0;
  }
}

__global__ void k_cvt(const void* __restrict__ in, float* __restrict__ out, int n,
                      const int* __restrict__ flags) {
  int isf = flags[0];
  int i = blockIdx.x * blockDim.x + threadIdx.x;
  int stride = gridDim.x * blockDim.x;
  if (isf) {
    const float* p = (const float*)in;
    for (; i < n; i += stride) out[i] = p[i];
  } else {
    const unsigned short* p = (const unsigned short*)in;
    for (; i < n; i += stride) out[i] = bf2f(p[i]);
  }
}

struct PBatch { const void* src[20]; int off[21]; };

__global__ void k_cvt_params(PBatch b, float* __restrict__ out, const int* __restrict__ flags) {
  int isf = flags[0];
  int total = b.off[20];
  for (int i = blockIdx.x * blockDim.x + threadIdx.x; i < total; i += gridDim.x * blockDim.x) {
    int k = 0;
    while (i >= b.off[k + 1]) k++;
    int j = i - b.off[k];
    out[i] = isf ? ((const float*)b.src[k])[j] : bf2f(((const unsigned short*)b.src[k])[j]);
  }
}

// x (f32 or bf16 per flag) -> Ahi/Alo bf16-split, 4 elems per thread
__global__ void k_split_x(const void* __restrict__ in, unsigned short* __restrict__ Ahi,
                          unsigned short* __restrict__ Alo, const int* __restrict__ flags) {
  int isf = flags[0];
  int i = blockIdx.x * blockDim.x + threadIdx.x;
  if (i >= NN * DIM / 4) return;
  float v[4];
  if (isf) {
    float4 t = reinterpret_cast<const float4*>(in)[i];
    v[0] = t.x; v[1] = t.y; v[2] = t.z; v[3] = t.w;
  } else {
    ushort4 t = reinterpret_cast<const ushort4*>(in)[i];
    v[0] = bf2f(t.x); v[1] = bf2f(t.y); v[2] = bf2f(t.z); v[3] = bf2f(t.w);
  }
  ushort4 h, l;
  split2(v[0], h.x, l.x); split2(v[1], h.y, l.y);
  split2(v[2], h.z, l.z); split2(v[3], h.w, l.w);
  reinterpret_cast<ushort4*>(Ahi)[i] = h;
  reinterpret_cast<ushort4*>(Alo)[i] = l;
}

struct WPtrs { const float* W[8]; };

// W[m] (256x256 row-major, k x col) -> packed transposed bf16 hi/lo [m][col][k]
__global__ void k_split_w(WPtrs wp, const float* __restrict__ Pf,
                          unsigned short* __restrict__ Bhi, unsigned short* __restrict__ Blo) {
  int i = blockIdx.x * blockDim.x + threadIdx.x;  // m*65536 + col*256 + k
  if (i >= 8 * 65536) return;
  int m = i >> 16;
  int col = (i >> 8) & 255;
  int k = i & 255;
  float v = wp.W[m][k * 256 + col];
  unsigned short h, l;
  split2(v, h, l);
  Bhi[i] = h; Blo[i] = l;
}

struct BPtrs { const float* B[8]; };

__global__ void k_bias(BPtrs bp, float* __restrict__ bvec) {
  int i = blockIdx.x * blockDim.x + threadIdx.x;  // g*1024 + mat*256 + c
  if (i >= 2048) return;
  int m = i >> 8;  // 0..7
  bvec[i] = bp.B[m][i & 255];
}

__global__ void k_idx_count(const int* __restrict__ ei, int* __restrict__ s32,
                            int* __restrict__ d32, int* __restrict__ counts,
                            const int* __restrict__ flags) {
  int i64 = flags[1];
  int i = blockIdx.x * blockDim.x + threadIdx.x;
  if (i < EE) {
    int s, d;
    if (i64) { s = ei[2 * i]; d = ei[2 * (EE + i)]; }
    else     { s = ei[i];     d = ei[EE + i]; }
    s32[i] = s; d32[i] = d;
    atomicAdd(&counts[d], 1);
  }
}

__global__ __launch_bounds__(256) void k_scan1(const int* __restrict__ counts,
                                               int* __restrict__ tmpoff,
                                               int* __restrict__ bsum) {
  __shared__ int s[256];
  int t = threadIdx.x;
  int i = blockIdx.x * 256 + t;
  int v = (i < NN) ? counts[i] : 0;
  s[t] = v;
  __syncthreads();
  for (int off = 1; off < 256; off <<= 1) {
    int x = (t >= off) ? s[t - off] : 0;
    __syncthreads();
    s[t] += x;
    __syncthreads();
  }
  if (i < NN) tmpoff[i] = s[t] - v;
  if (t == 255) bsum[blockIdx.x] = s[255];
}

__global__ void k_scan2(const int* __restrict__ bsum, int* __restrict__ bbase) {
  int lane = threadIdx.x;
  int v = (lane < SCANB) ? bsum[lane] : 0;
  int incl = v;
  #pragma unroll
  for (int off = 1; off < 64; off <<= 1) {
    int t = __shfl_up(incl, off);
    if (lane >= off) incl += t;
  }
  if (lane < SCANB) bbase[lane] = incl - v;
}

__global__ __launch_bounds__(256) void k_scan3(const int* __restrict__ tmpoff,
                                               const int* __restrict__ bbase,
                                               int* __restrict__ offsets,
                                               int* __restrict__ cursor) {
  int i = blockIdx.x * 256 + threadIdx.x;
  if (i < NN) {
    int o = tmpoff[i] + bbase[i >> 8];
    offsets[i] = o;
    cursor[i] = o;
  }
  if (i == 0) offsets[NN] = EE;
}

__global__ void k_fill_sort(const int* __restrict__ d32, const int* __restrict__ s32,
                            const float* __restrict__ ewf, int* __restrict__ cursor,
                            int* __restrict__ srcS, float* __restrict__ wS) {
  int i = blockIdx.x * blockDim.x + threadIdx.x;
  if (i < EE) {
    int p = atomicAdd(&cursor[d32[i]], 1);
    srcS[p] = s32[i];
    wS[p] = ewf[i];
  }
}

// MFMA GEMM: C[NN][1024] = A[NN][256] @ B[256][1024] + bias, via bf16 hi/lo 3-pass.
// Block 256 thr = 4 waves; tile 32 rows x 256 cols; wave = 32x64 (2 rowfrag x 4 colfrag).
// A frag: lane&15 = row, (lane>>4)*8 = k-group (16B contiguous). B pre-transposed k-contig.
__global__ __launch_bounds__(256) void k_gemm_mfma(
    const unsigned short* __restrict__ Ahi, const unsigned short* __restrict__ Alo,
    const unsigned short* __restrict__ Bhi, const unsigned short* __restrict__ Blo,
    const float* __restrict__ bvec, float* __restrict__ C) {
  int tid = (int)threadIdx.x;
  int wave = tid >> 6, lane = tid & 63;
  int lr = lane & 15;
  int kg = (lane >> 4) << 3;
  int rowBase = blockIdx.x << 5;
  int colBase = (blockIdx.y << 8) + (wave << 6);
  const unsigned short* a0 = Ahi + (size_t)(rowBase + lr) * 256 + kg;
  const unsigned short* a1 = Alo + (size_t)(rowBase + lr) * 256 + kg;
  const unsigned short* b0 = Bhi + (size_t)(colBase + lr) * 256 + kg;
  const unsigned short* b1 = Blo + (size_t)(colBase + lr) * 256 + kg;
  f32x4 acc[2][4] = {};
  #pragma unroll
  for (int ks = 0; ks < 256; ks += 32) {
    s16x8 ah0 = *reinterpret_cast<const s16x8*>(a0 + ks);
    s16x8 ah1 = *reinterpret_cast<const s16x8*>(a0 + 16 * 256 + ks);
    s16x8 al0 = *reinterpret_cast<const s16x8*>(a1 + ks);
    s16x8 al1 = *reinterpret_cast<const s16x8*>(a1 + 16 * 256 + ks);
    s16x8 bh[4], bl[4];
    #pragma unroll
    for (int cf = 0; cf < 4; ++cf) {
      bh[cf] = *reinterpret_cast<const s16x8*>(b0 + cf * 16 * 256 + ks);
      bl[cf] = *reinterpret_cast<const s16x8*>(b1 + cf * 16 * 256 + ks);
    }
    #pragma unroll
    for (int cf = 0; cf < 4; ++cf) {
      acc[0][cf] = __builtin_amdgcn_mfma_f32_16x16x32_bf16(ah0, bh[cf], acc[0][cf], 0, 0, 0);
      acc[0][cf] = __builtin_amdgcn_mfma_f32_16x16x32_bf16(ah0, bl[cf], acc[0][cf], 0, 0, 0);
      acc[0][cf] = __builtin_amdgcn_mfma_f32_16x16x32_bf16(al0, bh[cf], acc[0][cf], 0, 0, 0);
      acc[1][cf] = __builtin_amdgcn_mfma_f32_16x16x32_bf16(ah1, bh[cf], acc[1][cf], 0, 0, 0);
      acc[1][cf] = __builtin_amdgcn_mfma_f32_16x16x32_bf16(ah1, bl[cf], acc[1][cf], 0, 0, 0);
      acc[1][cf] = __builtin_amdgcn_mfma_f32_16x16x32_bf16(al1, bh[cf], acc[1][cf], 0, 0, 0);
    }
  }
  int rj = (lane >> 4) << 2;
  #pragma unroll
  for (int rf = 0; rf < 2; ++rf) {
    #pragma unroll
    for (int cf = 0; cf < 4; ++cf) {
      int col = colBase + cf * 16 + lr;
      float bb = bvec[col];
      #pragma unroll
      for (int j = 0; j < 4; ++j) {
        int row = rowBase + rf * 16 + rj + j;
        if (row < NN) C[(size_t)row * 1024 + col] = acc[rf][cf][j] + bb;
      }
    }
  }
}

#define ATT_STEP(KK, VV, WW) do { \
    float part = q4.x * fmaf(WW, we4.x, KK.x) + q4.y * fmaf(WW, we4.y, KK.y) \
               + q4.z * fmaf(WW, we4.z, KK.z) + q4.w * fmaf(WW, we4.w, KK.w); \
    part += __shfl_xor(part, 1); \
    part += __shfl_xor(part, 2); \
    part += __shfl_xor(part, 4); \
    float alpha = part * 0.17677669529663687f; \
    float nm = fmaxf(m, alpha); \
    float sc = __expf(m - nm); \
    float pe = __expf(alpha - nm); \
    l = l * sc + pe; \
    a0 = fmaf(a0, sc, pe * fmaf(WW, we4.x, VV.x)); \
    a1 = fmaf(a1, sc, pe * fmaf(WW, we4.y, VV.y)); \
    a2 = fmaf(a2, sc, pe * fmaf(WW, we4.z, VV.z)); \
    a3 = fmaf(a3, sc, pe * fmaf(WW, we4.w, VV.w)); \
    m = nm; \
  } while (0)

// one wave per node over packed QKVX[NN][1024] = Q|K|V|XR; fused gate epilogue.
// Output: either d_out f32 (final) or next layer's Ahi/Alo bf16-split.
__global__ __launch_bounds__(256) void k_attn(
    const float* __restrict__ QKVX, const float* __restrict__ We,
    const float* __restrict__ Wb, const int* __restrict__ srcS,
    const float* __restrict__ wS, const int* __restrict__ offsets,
    unsigned short* __restrict__ Ahi, unsigned short* __restrict__ Alo,
    float* __restrict__ FinalOut) {
  int wid = (int)threadIdx.x >> 6, lane = (int)threadIdx.x & 63;
  int node = blockIdx.x * 4 + wid;
  if (node >= NN) return;
  int d0 = lane * 4;
  const float* base = QKVX + (size_t)node * 1024;
  const float4 q4 = *reinterpret_cast<const float4*>(base + d0);
  const float4 x4 = *reinterpret_cast<const float4*>(base + 768 + d0);
  const float4 we4 = *reinterpret_cast<const float4*>(&We[d0]);
  const float4 wo = *reinterpret_cast<const float4*>(&Wb[d0]);
  const float4 wx = *reinterpret_cast<const float4*>(&Wb[DIM + d0]);
  const float4 wd = *reinterpret_cast<const float4*>(&Wb[2 * DIM + d0]);
  int beg = offsets[node], end = offsets[node + 1];
  beg = __builtin_amdgcn_readfirstlane(beg);
  end = __builtin_amdgcn_readfirstlane(end);
  float m = -INFINITY, l = 0.f, a0 = 0.f, a1 = 0.f, a2 = 0.f, a3 = 0.f;
  if (end > beg) {
    int pLast = end - 1;
    int sA = srcS[beg];
    float wA = wS[beg];
    int p1 = (beg + 1 <= pLast) ? beg + 1 : pLast;
    int sB = srcS[p1];
    float wB = wS[p1];
    const float* rA = QKVX + (size_t)sA * 1024 + d0;
    const float* rB = QKVX + (size_t)sB * 1024 + d0;
    float4 kA = *reinterpret_cast<const float4*>(rA + 256);
    float4 vA = *reinterpret_cast<const float4*>(rA + 512);
    float4 kB = *reinterpret_cast<const float4*>(rB + 256);
    float4 vB = *reinterpret_cast<const float4*>(rB + 512);
    int p = beg;
    #pragma unroll 2
    for (; p + 2 < end; ++p) {
      int sN = srcS[p + 2];
      float wN = wS[p + 2];
      const float* rN = QKVX + (size_t)sN * 1024 + d0;
      float4 kN = *reinterpret_cast<const float4*>(rN + 256);
      float4 vN = *reinterpret_cast<const float4*>(rN + 512);
      ATT_STEP(kA, vA, wA);
      kA = kB; vA = vB; wA = wB;
      kB = kN; vB = vN; wB = wN;
    }
    ATT_STEP(kA, vA, wA);
    if (p + 1 < end) ATT_STEP(kB, vB, wB);
  }
  float inv = 1.f / (l + 1e-16f);
  float o0 = a0 * inv, o1 = a1 * inv, o2 = a2 * inv, o3 = a3 * inv;
  float part = o0 * wo.x + o1 * wo.y + o2 * wo.z + o3 * wo.w
             + x4.x * wx.x + x4.y * wx.y + x4.z * wx.z + x4.w * wx.w
             + (o0 - x4.x) * wd.x + (o1 - x4.y) * wd.y
             + (o2 - x4.z) * wd.z + (o3 - x4.w) * wd.w;
  #pragma unroll
  for (int msk = 1; msk < 64; msk <<= 1) part += __shfl_xor(part, msk);
  float beta = 1.f / (1.f + __expf(-part));
  float h0 = beta * x4.x + (1.f - beta) * o0;
  float h1 = beta * x4.y + (1.f - beta) * o1;
  float h2 = beta * x4.z + (1.f - beta) * o2;
  float h3 = beta * x4.w + (1.f - beta) * o3;
  if (FinalOut) {
    float4 h; h.x = h0; h.y = h1; h.z = h2; h.w = h3;
    *reinterpret_cast<float4*>(&FinalOut[(size_t)node * DIM + d0]) = h;
  } else {
    ushort4 hh, ll;
    split2(h0, hh.x, ll.x); split2(h1, hh.y, ll.y);
    split2(h2, hh.z, ll.z); split2(h3, hh.w, ll.w);
    *reinterpret_cast<ushort4*>(&Ahi[(size_t)node * DIM + d0]) = hh;
    *reinterpret_cast<ushort4*>(&Alo[(size_t)node * DIM + d0]) = ll;
  }
}

static inline size_t align256(size_t v) { return (v + 255) & ~(size_t)255; }

extern "C" void kernel_launch(void* const* d_in, const int* in_sizes, int n_in,
                              void* d_out, int out_size, void* d_ws, size_t ws_size,
                              hipStream_t stream) {
  const void* x = d_in[0];
  const int* eidx = (const int*)d_in[1];
  const void* ew = d_in[2];

  char* w = (char*)d_ws;
  size_t pos = 0;
  int* flags = (int*)(w + pos); pos = align256(pos + 2 * sizeof(int));
  float* QKVX = (float*)(w + pos); pos = align256(pos + (size_t)NN * 1024 * 4);
  unsigned short* Ahi = (unsigned short*)(w + pos); pos = align256(pos + (size_t)NROWS * DIM * 2);
  unsigned short* Alo = (unsigned short*)(w + pos); pos = align256(pos + (size_t)NROWS * DIM * 2);
  unsigned short* Bhi = (unsigned short*)(w + pos); pos = align256(pos + (size_t)8 * 65536 * 2);
  unsigned short* Blo = (unsigned short*)(w + pos); pos = align256(pos + (size_t)8 * 65536 * 2);
  float* bvec = (float*)(w + pos);  pos = align256(pos + 2048 * 4);
  float* ewf = (float*)(w + pos);  pos = align256(pos + (size_t)EE * 4);
  int* s32   = (int*)(w + pos);    pos = align256(pos + (size_t)EE * 4);
  int* d32   = (int*)(w + pos);    pos = align256(pos + (size_t)EE * 4);
  int* srcS  = (int*)(w + pos);    pos = align256(pos + (size_t)EE * 4);
  float* wS  = (float*)(w + pos);  pos = align256(pos + (size_t)EE * 4);
  int* counts  = (int*)(w + pos);  pos = align256(pos + (size_t)NN * 4);
  int* offsets = (int*)(w + pos);  pos = align256(pos + (size_t)(NN + 1) * 4);
  int* cursor  = (int*)(w + pos);  pos = align256(pos + (size_t)NN * 4);
  int* tmpoff  = (int*)(w + pos);  pos = align256(pos + (size_t)NN * 4);
  int* bsum    = (int*)(w + pos);  pos = align256(pos + 64 * 4);
  int* bbase   = (int*)(w + pos);  pos = align256(pos + 64 * 4);
  float* Pf    = (float*)(w + pos);

  PBatch pb;
  int off = 0;
  for (int i = 0; i < 20; ++i) {
    pb.src[i] = d_in[3 + i];
    pb.off[i] = off;
    off += in_sizes[3 + i];
  }
  pb.off[20] = off;

  k_detect<<<1, 64, 0, stream>>>((const unsigned int*)x, eidx, flags);
  hipMemsetAsync(counts, 0, (size_t)NN * 4, stream);
  k_idx_count<<<(EE + 255) / 256, 256, 0, stream>>>(eidx, s32, d32, counts, flags);
  k_cvt<<<1250, 256, 0, stream>>>(ew, ewf, EE, flags);
  k_scan1<<<SCANB, 256, 0, stream>>>(counts, tmpoff, bsum);
  k_scan2<<<1, 64, 0, stream>>>(bsum, bbase);
  k_scan3<<<SCANB, 256, 0, stream>>>(tmpoff, bbase, offsets, cursor);
  k_fill_sort<<<(EE + 255) / 256, 256, 0, stream>>>(d32, s32, ewf, cursor, srcS, wS);
  k_cvt_params<<<2064, 256, 0, stream>>>(pb, Pf, flags);

  const float* P[20];
  for (int i = 0; i < 20; ++i) P[i] = Pf + pb.off[i];

  // pack W/bias: matrices {Wq,Wk,Wv,Wskip} x {p1,p2} -> transposed bf16 hi/lo
  WPtrs wp;
  BPtrs bp;
  for (int g = 0; g < 2; ++g) {
    const float* const* pp = &P[g * 10];
    wp.W[g * 4 + 0] = pp[0]; wp.W[g * 4 + 1] = pp[2];
    wp.W[g * 4 + 2] = pp[4]; wp.W[g * 4 + 3] = pp[7];
    bp.B[g * 4 + 0] = pp[1]; bp.B[g * 4 + 1] = pp[3];
    bp.B[g * 4 + 2] = pp[5]; bp.B[g * 4 + 3] = pp[8];
  }
  k_split_w<<<(8 * 65536 + 255) / 256, 256, 0, stream>>>(wp, Pf, Bhi, Blo);
  k_bias<<<8, 256, 0, stream>>>(bp, bvec);
  k_split_x<<<(NN * DIM / 4 + 255) / 256, 256, 0, stream>>>(x, Ahi, Alo, flags);

  for (int layer = 0; layer < 3; ++layer) {
    int g = (layer == 0) ? 0 : 1;
    const float* const* pp = &P[g * 10];
    k_gemm_mfma<<<dim3(NROWS / 32, 4), 256, 0, stream>>>(
        Ahi, Alo, Bhi + (size_t)g * 4 * 65536, Blo + (size_t)g * 4 * 65536,
        bvec + g * 1024, QKVX);
    k_attn<<<(NN + 3) / 4, 256, 0, stream>>>(QKVX, pp[6], pp[9],
        srcS, wS, offsets, Ahi, Alo, (layer == 2) ? (float*)d_out : nullptr);
  }
}

// Round 6
// 394.499 us; speedup vs baseline: 2.0446x; 1.2872x over previous
//
#include <hip/hip_runtime.h>
#include <hip/hip_bf16.h>
#include <math.h>

#define NN 10000
#define EE 320000
#define DIM 256
#define NROWS 10016   // NN padded to 32
#define SCANB 40      // ceil(NN/256)

typedef __attribute__((ext_vector_type(8))) short s16x8;
typedef __attribute__((ext_vector_type(4))) float f32x4;
typedef __attribute__((ext_vector_type(4))) _Float16 f16x4;

__device__ __forceinline__ float bf2f(unsigned short u) {
  union { unsigned int ui; float f; } cv;
  cv.ui = ((unsigned int)u) << 16;
  return cv.f;
}

__device__ __forceinline__ unsigned short f2bf(float f) {
  union { float f; unsigned int u; } cv; cv.f = f;
  unsigned int u = cv.u;
  u += 0x7fffu + ((u >> 16) & 1u);
  return (unsigned short)(u >> 16);
}

// split f32 into hi+lo bf16 (hi = rne(v), lo = rne(v - hi))
__device__ __forceinline__ void split2(float v, unsigned short& hi, unsigned short& lo) {
  hi = f2bf(v);
  lo = f2bf(v - bf2f(hi));
}

// one wave: decide {float inputs f32 vs bf16} and {edge_index int64 vs int32}
__global__ void k_detect(const unsigned int* __restrict__ xw, const int* __restrict__ ei,
                         int* __restrict__ flags) {
  int lane = threadIdx.x;
  int wild = 0;
  for (int t = 0; t < 16; ++t) {
    unsigned int w = xw[t * 64 + lane];
    unsigned int lo = w & 0xffffu;
    float f = bf2f((unsigned short)lo);
    float af = fabsf(f);
    if (lo != 0u && (af > 1e4f || af < 1e-30f)) wild++;
  }
  #pragma unroll
  for (int m = 1; m < 64; m <<= 1) wild += __shfl_xor(wild, m);
  int zeros = 0;
  for (int t = 0; t < 2; ++t) {
    if (ei[(t * 64 + lane) * 2 + 1] == 0) zeros++;
  }
  #pragma unroll
  for (int m = 1; m < 64; m <<= 1) zeros += __shfl_xor(zeros, m);
  if (lane == 0) {
    flags[0] = (wild > 100) ? 1 : 0;
    flags[1] = (zeros > 100) ? 1 : 0;
  }
}

struct PBatch { const void* src[20]; int off[21]; };

__global__ void k_cvt_params(PBatch b, float* __restrict__ out, const int* __restrict__ flags) {
  int isf = flags[0];
  int total = b.off[20];
  for (int i = blockIdx.x * blockDim.x + threadIdx.x; i < total; i += gridDim.x * blockDim.x) {
    int k = 0;
    while (i >= b.off[k + 1]) k++;
    int j = i - b.off[k];
    out[i] = isf ? ((const float*)b.src[k])[j] : bf2f(((const unsigned short*)b.src[k])[j]);
  }
}

// x (f32 or bf16 per flag) -> Ahi/Alo bf16-split, 4 elems per thread
__global__ void k_split_x(const void* __restrict__ in, unsigned short* __restrict__ Ahi,
                          unsigned short* __restrict__ Alo, const int* __restrict__ flags) {
  int isf = flags[0];
  int i = blockIdx.x * blockDim.x + threadIdx.x;
  if (i >= NN * DIM / 4) return;
  float v[4];
  if (isf) {
    float4 t = reinterpret_cast<const float4*>(in)[i];
    v[0] = t.x; v[1] = t.y; v[2] = t.z; v[3] = t.w;
  } else {
    ushort4 t = reinterpret_cast<const ushort4*>(in)[i];
    v[0] = bf2f(t.x); v[1] = bf2f(t.y); v[2] = bf2f(t.z); v[3] = bf2f(t.w);
  }
  ushort4 h, l;
  split2(v[0], h.x, l.x); split2(v[1], h.y, l.y);
  split2(v[2], h.z, l.z); split2(v[3], h.w, l.w);
  reinterpret_cast<ushort4*>(Ahi)[i] = h;
  reinterpret_cast<ushort4*>(Alo)[i] = l;
}

struct WPtrs { const float* W[8]; };

// W[m] (256x256 row-major, k x col) -> packed transposed bf16 hi/lo [m][col][k]
__global__ void k_split_w(WPtrs wp, unsigned short* __restrict__ Bhi,
                          unsigned short* __restrict__ Blo) {
  int i = blockIdx.x * blockDim.x + threadIdx.x;  // m*65536 + col*256 + k
  if (i >= 8 * 65536) return;
  int m = i >> 16;
  int col = (i >> 8) & 255;
  int k = i & 255;
  float v = wp.W[m][k * 256 + col];
  unsigned short h, l;
  split2(v, h, l);
  Bhi[i] = h; Blo[i] = l;
}

struct BPtrs { const float* B[8]; };

__global__ void k_bias(BPtrs bp, float* __restrict__ bvec) {
  int i = blockIdx.x * blockDim.x + threadIdx.x;  // g*1024 + mat*256 + c
  if (i >= 2048) return;
  int m = i >> 8;  // 0..7
  bvec[i] = bp.B[m][i & 255];
}

__global__ void k_idx_count(const int* __restrict__ ei, int* __restrict__ s32,
                            int* __restrict__ d32, int* __restrict__ counts,
                            const int* __restrict__ flags) {
  int i64 = flags[1];
  int i = blockIdx.x * blockDim.x + threadIdx.x;
  if (i < EE) {
    int s, d;
    if (i64) { s = ei[2 * i]; d = ei[2 * (EE + i)]; }
    else     { s = ei[i];     d = ei[EE + i]; }
    s32[i] = s; d32[i] = d;
    atomicAdd(&counts[d], 1);
  }
}

__global__ __launch_bounds__(256) void k_scan1(const int* __restrict__ counts,
                                               int* __restrict__ tmpoff,
                                               int* __restrict__ bsum) {
  __shared__ int s[256];
  int t = threadIdx.x;
  int i = blockIdx.x * 256 + t;
  int v = (i < NN) ? counts[i] : 0;
  s[t] = v;
  __syncthreads();
  for (int off = 1; off < 256; off <<= 1) {
    int x = (t >= off) ? s[t - off] : 0;
    __syncthreads();
    s[t] += x;
    __syncthreads();
  }
  if (i < NN) tmpoff[i] = s[t] - v;
  if (t == 255) bsum[blockIdx.x] = s[255];
}

__global__ void k_scan2(const int* __restrict__ bsum, int* __restrict__ bbase) {
  int lane = threadIdx.x;
  int v = (lane < SCANB) ? bsum[lane] : 0;
  int incl = v;
  #pragma unroll
  for (int off = 1; off < 64; off <<= 1) {
    int t = __shfl_up(incl, off);
    if (lane >= off) incl += t;
  }
  if (lane < SCANB) bbase[lane] = incl - v;
}

__global__ __launch_bounds__(256) void k_scan3(const int* __restrict__ tmpoff,
                                               const int* __restrict__ bbase,
                                               int* __restrict__ offsets,
                                               int* __restrict__ cursor) {
  int i = blockIdx.x * 256 + threadIdx.x;
  if (i < NN) {
    int o = tmpoff[i] + bbase[i >> 8];
    offsets[i] = o;
    cursor[i] = o;
  }
  if (i == 0) offsets[NN] = EE;
}

__global__ void k_fill_sort(const int* __restrict__ d32, const int* __restrict__ s32,
                            const void* __restrict__ ew, int* __restrict__ cursor,
                            int* __restrict__ srcS, float* __restrict__ wS,
                            const int* __restrict__ flags) {
  int isf = flags[0];
  int i = blockIdx.x * blockDim.x + threadIdx.x;
  if (i < EE) {
    float wv = isf ? ((const float*)ew)[i] : bf2f(((const unsigned short*)ew)[i]);
    int p = atomicAdd(&cursor[d32[i]], 1);
    srcS[p] = s32[i];
    wS[p] = wv;
  }
}

// MFMA GEMM via bf16 hi/lo 3-pass. Block 256 thr = 4 waves; tile 32 rows x 256 cols.
// blockIdx.y = matrix: 0=Q (f32), 1=K (fp16 -> KV[.][0:256]), 2=V (fp16 -> KV[.][256:512]),
// 3=XR (f32). B pre-transposed k-contiguous.
__global__ __launch_bounds__(256) void k_gemm_mfma(
    const unsigned short* __restrict__ Ahi, const unsigned short* __restrict__ Alo,
    const unsigned short* __restrict__ Bhi, const unsigned short* __restrict__ Blo,
    const float* __restrict__ bvec, float* __restrict__ Qf, _Float16* __restrict__ KVh,
    float* __restrict__ XRf) {
  int tid = (int)threadIdx.x;
  int wave = tid >> 6, lane = tid & 63;
  int lr = lane & 15;
  int kg = (lane >> 4) << 3;
  int mat = blockIdx.y;
  int rowBase = blockIdx.x << 5;
  int colBase = (mat << 8) + (wave << 6);
  const unsigned short* a0 = Ahi + (size_t)(rowBase + lr) * 256 + kg;
  const unsigned short* a1 = Alo + (size_t)(rowBase + lr) * 256 + kg;
  const unsigned short* b0 = Bhi + (size_t)(colBase + lr) * 256 + kg;
  const unsigned short* b1 = Blo + (size_t)(colBase + lr) * 256 + kg;
  f32x4 acc[2][4] = {};
  #pragma unroll
  for (int ks = 0; ks < 256; ks += 32) {
    s16x8 ah0 = *reinterpret_cast<const s16x8*>(a0 + ks);
    s16x8 ah1 = *reinterpret_cast<const s16x8*>(a0 + 16 * 256 + ks);
    s16x8 al0 = *reinterpret_cast<const s16x8*>(a1 + ks);
    s16x8 al1 = *reinterpret_cast<const s16x8*>(a1 + 16 * 256 + ks);
    s16x8 bh[4], bl[4];
    #pragma unroll
    for (int cf = 0; cf < 4; ++cf) {
      bh[cf] = *reinterpret_cast<const s16x8*>(b0 + cf * 16 * 256 + ks);
      bl[cf] = *reinterpret_cast<const s16x8*>(b1 + cf * 16 * 256 + ks);
    }
    #pragma unroll
    for (int cf = 0; cf < 4; ++cf) {
      acc[0][cf] = __builtin_amdgcn_mfma_f32_16x16x32_bf16(ah0, bh[cf], acc[0][cf], 0, 0, 0);
      acc[0][cf] = __builtin_amdgcn_mfma_f32_16x16x32_bf16(ah0, bl[cf], acc[0][cf], 0, 0, 0);
      acc[0][cf] = __builtin_amdgcn_mfma_f32_16x16x32_bf16(al0, bh[cf], acc[0][cf], 0, 0, 0);
      acc[1][cf] = __builtin_amdgcn_mfma_f32_16x16x32_bf16(ah1, bh[cf], acc[1][cf], 0, 0, 0);
      acc[1][cf] = __builtin_amdgcn_mfma_f32_16x16x32_bf16(ah1, bl[cf], acc[1][cf], 0, 0, 0);
      acc[1][cf] = __builtin_amdgcn_mfma_f32_16x16x32_bf16(al1, bh[cf], acc[1][cf], 0, 0, 0);
    }
  }
  int rj = (lane >> 4) << 2;
  int colLoc = (wave << 6);  // column within the 256-wide matrix
  #pragma unroll
  for (int rf = 0; rf < 2; ++rf) {
    #pragma unroll
    for (int cf = 0; cf < 4; ++cf) {
      int col = colLoc + cf * 16 + lr;
      float bb = bvec[(mat << 8) + col];
      #pragma unroll
      for (int j = 0; j < 4; ++j) {
        int row = rowBase + rf * 16 + rj + j;
        if (row < NN) {
          float val = acc[rf][cf][j] + bb;
          if (mat == 0)      Qf[(size_t)row * DIM + col] = val;
          else if (mat == 3) XRf[(size_t)row * DIM + col] = val;
          else KVh[(size_t)row * 512 + ((mat == 2) ? 256 : 0) + col] = (_Float16)val;
        }
      }
    }
  }
}

#define ATT_STEP(KK, VV, WW) do { \
    float part = q4.x * fmaf(WW, we4.x, (float)KK[0]) + q4.y * fmaf(WW, we4.y, (float)KK[1]) \
               + q4.z * fmaf(WW, we4.z, (float)KK[2]) + q4.w * fmaf(WW, we4.w, (float)KK[3]); \
    part += __shfl_xor(part, 1); \
    part += __shfl_xor(part, 2); \
    part += __shfl_xor(part, 4); \
    float alpha = part * 0.17677669529663687f; \
    float nm = fmaxf(m, alpha); \
    float sc = __expf(m - nm); \
    float pe = __expf(alpha - nm); \
    l = l * sc + pe; \
    a0 = fmaf(a0, sc, pe * fmaf(WW, we4.x, (float)VV[0])); \
    a1 = fmaf(a1, sc, pe * fmaf(WW, we4.y, (float)VV[1])); \
    a2 = fmaf(a2, sc, pe * fmaf(WW, we4.z, (float)VV[2])); \
    a3 = fmaf(a3, sc, pe * fmaf(WW, we4.w, (float)VV[3])); \
    m = nm; \
  } while (0)

// one wave per node; 64 lanes = 8 heads x 8 lanes x 4 dims; fused gate epilogue.
// K/V gathered as fp16 from packed KV rows (1 KB/node).
__global__ __launch_bounds__(256) void k_attn(
    const float* __restrict__ Qf, const _Float16* __restrict__ KVh,
    const float* __restrict__ XRf, const float* __restrict__ We,
    const float* __restrict__ Wb, const int* __restrict__ srcS,
    const float* __restrict__ wS, const int* __restrict__ offsets,
    unsigned short* __restrict__ Ahi, unsigned short* __restrict__ Alo,
    float* __restrict__ FinalOut) {
  int wid = (int)threadIdx.x >> 6, lane = (int)threadIdx.x & 63;
  int node = blockIdx.x * 4 + wid;
  if (node >= NN) return;
  int d0 = lane * 4;
  const float4 q4 = *reinterpret_cast<const float4*>(&Qf[(size_t)node * DIM + d0]);
  const float4 x4 = *reinterpret_cast<const float4*>(&XRf[(size_t)node * DIM + d0]);
  const float4 we4 = *reinterpret_cast<const float4*>(&We[d0]);
  const float4 wo = *reinterpret_cast<const float4*>(&Wb[d0]);
  const float4 wx = *reinterpret_cast<const float4*>(&Wb[DIM + d0]);
  const float4 wd = *reinterpret_cast<const float4*>(&Wb[2 * DIM + d0]);
  int beg = offsets[node], end = offsets[node + 1];
  beg = __builtin_amdgcn_readfirstlane(beg);
  end = __builtin_amdgcn_readfirstlane(end);
  float m = -INFINITY, l = 0.f, a0 = 0.f, a1 = 0.f, a2 = 0.f, a3 = 0.f;
  if (end > beg) {
    int pLast = end - 1;
    int sA = srcS[beg];
    float wA = wS[beg];
    int p1 = (beg + 1 <= pLast) ? beg + 1 : pLast;
    int sB = srcS[p1];
    float wB = wS[p1];
    const _Float16* rA = KVh + (size_t)sA * 512 + d0;
    const _Float16* rB = KVh + (size_t)sB * 512 + d0;
    f16x4 kA = *reinterpret_cast<const f16x4*>(rA);
    f16x4 vA = *reinterpret_cast<const f16x4*>(rA + 256);
    f16x4 kB = *reinterpret_cast<const f16x4*>(rB);
    f16x4 vB = *reinterpret_cast<const f16x4*>(rB + 256);
    int p = beg;
    #pragma unroll 2
    for (; p + 2 < end; ++p) {
      int sN = srcS[p + 2];
      float wN = wS[p + 2];
      const _Float16* rN = KVh + (size_t)sN * 512 + d0;
      f16x4 kN = *reinterpret_cast<const f16x4*>(rN);
      f16x4 vN = *reinterpret_cast<const f16x4*>(rN + 256);
      ATT_STEP(kA, vA, wA);
      kA = kB; vA = vB; wA = wB;
      kB = kN; vB = vN; wB = wN;
    }
    ATT_STEP(kA, vA, wA);
    if (p + 1 < end) ATT_STEP(kB, vB, wB);
  }
  float inv = 1.f / (l + 1e-16f);
  float o0 = a0 * inv, o1 = a1 * inv, o2 = a2 * inv, o3 = a3 * inv;
  float part = o0 * wo.x + o1 * wo.y + o2 * wo.z + o3 * wo.w
             + x4.x * wx.x + x4.y * wx.y + x4.z * wx.z + x4.w * wx.w
             + (o0 - x4.x) * wd.x + (o1 - x4.y) * wd.y
             + (o2 - x4.z) * wd.z + (o3 - x4.w) * wd.w;
  #pragma unroll
  for (int msk = 1; msk < 64; msk <<= 1) part += __shfl_xor(part, msk);
  float beta = 1.f / (1.f + __expf(-part));
  float h0 = beta * x4.x + (1.f - beta) * o0;
  float h1 = beta * x4.y + (1.f - beta) * o1;
  float h2 = beta * x4.z + (1.f - beta) * o2;
  float h3 = beta * x4.w + (1.f - beta) * o3;
  if (FinalOut) {
    float4 h; h.x = h0; h.y = h1; h.z = h2; h.w = h3;
    *reinterpret_cast<float4*>(&FinalOut[(size_t)node * DIM + d0]) = h;
  } else {
    ushort4 hh, ll;
    split2(h0, hh.x, ll.x); split2(h1, hh.y, ll.y);
    split2(h2, hh.z, ll.z); split2(h3, hh.w, ll.w);
    *reinterpret_cast<ushort4*>(&Ahi[(size_t)node * DIM + d0]) = hh;
    *reinterpret_cast<ushort4*>(&Alo[(size_t)node * DIM + d0]) = ll;
  }
}

static inline size_t align256(size_t v) { return (v + 255) & ~(size_t)255; }

extern "C" void kernel_launch(void* const* d_in, const int* in_sizes, int n_in,
                              void* d_out, int out_size, void* d_ws, size_t ws_size,
                              hipStream_t stream) {
  const void* x = d_in[0];
  const int* eidx = (const int*)d_in[1];
  const void* ew = d_in[2];

  char* w = (char*)d_ws;
  size_t pos = 0;
  int* flags = (int*)(w + pos); pos = align256(pos + 2 * sizeof(int));
  float* Qf  = (float*)(w + pos); pos = align256(pos + (size_t)NROWS * DIM * 4);
  float* XRf = (float*)(w + pos); pos = align256(pos + (size_t)NROWS * DIM * 4);
  _Float16* KVh = (_Float16*)(w + pos); pos = align256(pos + (size_t)NROWS * 512 * 2);
  unsigned short* Ahi = (unsigned short*)(w + pos); pos = align256(pos + (size_t)NROWS * DIM * 2);
  unsigned short* Alo = (unsigned short*)(w + pos); pos = align256(pos + (size_t)NROWS * DIM * 2);
  unsigned short* Bhi = (unsigned short*)(w + pos); pos = align256(pos + (size_t)8 * 65536 * 2);
  unsigned short* Blo = (unsigned short*)(w + pos); pos = align256(pos + (size_t)8 * 65536 * 2);
  float* bvec = (float*)(w + pos);  pos = align256(pos + 2048 * 4);
  int* s32   = (int*)(w + pos);    pos = align256(pos + (size_t)EE * 4);
  int* d32   = (int*)(w + pos);    pos = align256(pos + (size_t)EE * 4);
  int* srcS  = (int*)(w + pos);    pos = align256(pos + (size_t)EE * 4);
  float* wS  = (float*)(w + pos);  pos = align256(pos + (size_t)EE * 4);
  int* counts  = (int*)(w + pos);  pos = align256(pos + (size_t)NN * 4);
  int* offsets = (int*)(w + pos);  pos = align256(pos + (size_t)(NN + 1) * 4);
  int* cursor  = (int*)(w + pos);  pos = align256(pos + (size_t)NN * 4);
  int* tmpoff  = (int*)(w + pos);  pos = align256(pos + (size_t)NN * 4);
  int* bsum    = (int*)(w + pos);  pos = align256(pos + 64 * 4);
  int* bbase   = (int*)(w + pos);  pos = align256(pos + 64 * 4);
  float* Pf    = (float*)(w + pos);

  PBatch pb;
  int off = 0;
  for (int i = 0; i < 20; ++i) {
    pb.src[i] = d_in[3 + i];
    pb.off[i] = off;
    off += in_sizes[3 + i];
  }
  pb.off[20] = off;

  k_detect<<<1, 64, 0, stream>>>((const unsigned int*)x, eidx, flags);
  hipMemsetAsync(counts, 0, (size_t)NN * 4, stream);
  k_idx_count<<<(EE + 255) / 256, 256, 0, stream>>>(eidx, s32, d32, counts, flags);
  k_scan1<<<SCANB, 256, 0, stream>>>(counts, tmpoff, bsum);
  k_scan2<<<1, 64, 0, stream>>>(bsum, bbase);
  k_scan3<<<SCANB, 256, 0, stream>>>(tmpoff, bbase, offsets, cursor);
  k_fill_sort<<<(EE + 255) / 256, 256, 0, stream>>>(d32, s32, ew, cursor, srcS, wS, flags);
  k_cvt_params<<<2064, 256, 0, stream>>>(pb, Pf, flags);

  const float* P[20];
  for (int i = 0; i < 20; ++i) P[i] = Pf + pb.off[i];

  WPtrs wp;
  BPtrs bp;
  for (int g = 0; g < 2; ++g) {
    const float* const* pp = &P[g * 10];
    wp.W[g * 4 + 0] = pp[0]; wp.W[g * 4 + 1] = pp[2];
    wp.W[g * 4 + 2] = pp[4]; wp.W[g * 4 + 3] = pp[7];
    bp.B[g * 4 + 0] = pp[1]; bp.B[g * 4 + 1] = pp[3];
    bp.B[g * 4 + 2] = pp[5]; bp.B[g * 4 + 3] = pp[8];
  }
  k_split_w<<<(8 * 65536 + 255) / 256, 256, 0, stream>>>(wp, Bhi, Blo);
  k_bias<<<8, 256, 0, stream>>>(bp, bvec);
  k_split_x<<<(NN * DIM / 4 + 255) / 256, 256, 0, stream>>>(x, Ahi, Alo, flags);

  for (int layer = 0; layer < 3; ++layer) {
    int g = (layer == 0) ? 0 : 1;
    const float* const* pp = &P[g * 10];
    k_gemm_mfma<<<dim3(NROWS / 32, 4), 256, 0, stream>>>(
        Ahi, Alo, Bhi + (size_t)g * 4 * 65536, Blo + (size_t)g * 4 * 65536,
        bvec + g * 1024, Qf, KVh, XRf);
    k_attn<<<(NN + 3) / 4, 256, 0, stream>>>(Qf, KVh, XRf, pp[6], pp[9],
        srcS, wS, offsets, Ahi, Alo, (layer == 2) ? (float*)d_out : nullptr);
  }
}

// Round 7
// 331.239 us; speedup vs baseline: 2.4351x; 1.1910x over previous
//
#include <hip/hip_runtime.h>
#include <hip/hip_bf16.h>
#include <math.h>

#define NN 10000
#define EE 320000
#define DIM 256
#define NROWS 10016   // NN padded to 32
#define SCANB 40      // ceil(NN/256)

typedef __attribute__((ext_vector_type(8))) _Float16 f16x8;
typedef __attribute__((ext_vector_type(4))) _Float16 f16x4;
typedef __attribute__((ext_vector_type(4))) float f32x4;

__device__ __forceinline__ float bf2f(unsigned short u) {
  union { unsigned int ui; float f; } cv;
  cv.ui = ((unsigned int)u) << 16;
  return cv.f;
}

// one wave: decide {float inputs f32 vs bf16} and {edge_index int64 vs int32}
__global__ void k_detect(const unsigned int* __restrict__ xw, const int* __restrict__ ei,
                         int* __restrict__ flags) {
  int lane = threadIdx.x;
  int wild = 0;
  for (int t = 0; t < 16; ++t) {
    unsigned int w = xw[t * 64 + lane];
    unsigned int lo = w & 0xffffu;
    float f = bf2f((unsigned short)lo);
    float af = fabsf(f);
    if (lo != 0u && (af > 1e4f || af < 1e-30f)) wild++;
  }
  #pragma unroll
  for (int m = 1; m < 64; m <<= 1) wild += __shfl_xor(wild, m);
  int zeros = 0;
  for (int t = 0; t < 2; ++t) {
    if (ei[(t * 64 + lane) * 2 + 1] == 0) zeros++;
  }
  #pragma unroll
  for (int m = 1; m < 64; m <<= 1) zeros += __shfl_xor(zeros, m);
  if (lane == 0) {
    flags[0] = (wild > 100) ? 1 : 0;
    flags[1] = (zeros > 100) ? 1 : 0;
  }
}

struct PBatch { const void* src[20]; int off[21]; };

__global__ void k_cvt_params(PBatch b, float* __restrict__ out, const int* __restrict__ flags) {
  int isf = flags[0];
  int total = b.off[20];
  for (int i = blockIdx.x * blockDim.x + threadIdx.x; i < total; i += gridDim.x * blockDim.x) {
    int k = 0;
    while (i >= b.off[k + 1]) k++;
    int j = i - b.off[k];
    out[i] = isf ? ((const float*)b.src[k])[j] : bf2f(((const unsigned short*)b.src[k])[j]);
  }
}

// x -> Ah/Al fp16 hi/lo, 4 elems per thread; zero-pads rows NN..NROWS
__global__ void k_split_x(const void* __restrict__ in, _Float16* __restrict__ Ah,
                          _Float16* __restrict__ Al, const int* __restrict__ flags) {
  int isf = flags[0];
  int i = blockIdx.x * blockDim.x + threadIdx.x;
  if (i >= NROWS * DIM / 4) return;
  f16x4 h, l;
  if (i >= NN * DIM / 4) {
    h = (f16x4)(_Float16)0.f;
    l = (f16x4)(_Float16)0.f;
  } else {
    float v[4];
    if (isf) {
      float4 t = reinterpret_cast<const float4*>(in)[i];
      v[0] = t.x; v[1] = t.y; v[2] = t.z; v[3] = t.w;
    } else {
      ushort4 t = reinterpret_cast<const ushort4*>(in)[i];
      v[0] = bf2f(t.x); v[1] = bf2f(t.y); v[2] = bf2f(t.z); v[3] = bf2f(t.w);
    }
    #pragma unroll
    for (int j = 0; j < 4; ++j) {
      _Float16 hh = (_Float16)v[j];
      h[j] = hh;
      l[j] = (_Float16)(v[j] - (float)hh);
    }
  }
  reinterpret_cast<f16x4*>(Ah)[i] = h;
  reinterpret_cast<f16x4*>(Al)[i] = l;
}

struct WPtrs { const float* W[8]; };

// W[m] (256x256 row-major, k x col) -> packed transposed fp16 [m][col][k]
__global__ void k_split_w(WPtrs wp, _Float16* __restrict__ Bh) {
  int i = blockIdx.x * blockDim.x + threadIdx.x;  // m*65536 + col*256 + k
  if (i >= 8 * 65536) return;
  int m = i >> 16;
  int col = (i >> 8) & 255;
  int k = i & 255;
  Bh[i] = (_Float16)wp.W[m][k * 256 + col];
}

struct BPtrs { const float* B[8]; };

__global__ void k_bias(BPtrs bp, float* __restrict__ bvec) {
  int i = blockIdx.x * blockDim.x + threadIdx.x;  // g*1024 + mat*256 + c
  if (i >= 2048) return;
  int m = i >> 8;  // 0..7
  bvec[i] = bp.B[m][i & 255];
}

__global__ void k_idx_count(const int* __restrict__ ei, int* __restrict__ s32,
                            int* __restrict__ d32, int* __restrict__ counts,
                            const int* __restrict__ flags) {
  int i64 = flags[1];
  int i = blockIdx.x * blockDim.x + threadIdx.x;
  if (i < EE) {
    int s, d;
    if (i64) { s = ei[2 * i]; d = ei[2 * (EE + i)]; }
    else     { s = ei[i];     d = ei[EE + i]; }
    s32[i] = s; d32[i] = d;
    atomicAdd(&counts[d], 1);
  }
}

__global__ __launch_bounds__(256) void k_scan1(const int* __restrict__ counts,
                                               int* __restrict__ tmpoff,
                                               int* __restrict__ bsum) {
  __shared__ int s[256];
  int t = threadIdx.x;
  int i = blockIdx.x * 256 + t;
  int v = (i < NN) ? counts[i] : 0;
  s[t] = v;
  __syncthreads();
  for (int off = 1; off < 256; off <<= 1) {
    int x = (t >= off) ? s[t - off] : 0;
    __syncthreads();
    s[t] += x;
    __syncthreads();
  }
  if (i < NN) tmpoff[i] = s[t] - v;
  if (t == 255) bsum[blockIdx.x] = s[255];
}

__global__ void k_scan2(const int* __restrict__ bsum, int* __restrict__ bbase) {
  int lane = threadIdx.x;
  int v = (lane < SCANB) ? bsum[lane] : 0;
  int incl = v;
  #pragma unroll
  for (int off = 1; off < 64; off <<= 1) {
    int t = __shfl_up(incl, off);
    if (lane >= off) incl += t;
  }
  if (lane < SCANB) bbase[lane] = incl - v;
}

__global__ __launch_bounds__(256) void k_scan3(const int* __restrict__ tmpoff,
                                               const int* __restrict__ bbase,
                                               int* __restrict__ offsets,
                                               int* __restrict__ cursor) {
  int i = blockIdx.x * 256 + threadIdx.x;
  if (i < NN) {
    int o = tmpoff[i] + bbase[i >> 8];
    offsets[i] = o;
    cursor[i] = o;
  }
  if (i == 0) offsets[NN] = EE;
}

__global__ void k_fill_sort(const int* __restrict__ d32, const int* __restrict__ s32,
                            const void* __restrict__ ew, int* __restrict__ cursor,
                            int* __restrict__ srcS, float* __restrict__ wS,
                            const int* __restrict__ flags) {
  int isf = flags[0];
  int i = blockIdx.x * blockDim.x + threadIdx.x;
  if (i < EE) {
    float wv = isf ? ((const float*)ew)[i] : bf2f(((const unsigned short*)ew)[i]);
    int p = atomicAdd(&cursor[d32[i]], 1);
    srcS[p] = s32[i];
    wS[p] = wv;
  }
}

// fp16 MFMA GEMM. Block 256 thr = 4 waves; tile 32 rows x 256 cols (one matrix).
// blockIdx.y = matrix: 0=Q (f32), 1=K (fp16 -> KV[.][0:256]), 2=V (fp16 -> KV[.][256:512]),
// 3=XR (f32, 2-pass: Ah*B + Al*B). B pre-transposed k-contiguous fp16.
__global__ __launch_bounds__(256, 4) void k_gemm_mfma(
    const _Float16* __restrict__ Ah, const _Float16* __restrict__ Al,
    const _Float16* __restrict__ Bh, const float* __restrict__ bvec,
    float* __restrict__ Qf, _Float16* __restrict__ KVh, float* __restrict__ XRf) {
  int tid = (int)threadIdx.x;
  int wave = tid >> 6, lane = tid & 63;
  int lr = lane & 15;
  int kg = (lane >> 4) << 3;
  int mat = blockIdx.y;
  int rowBase = blockIdx.x << 5;
  int colBase = (mat << 8) + (wave << 6);
  const _Float16* a0 = Ah + (size_t)(rowBase + lr) * 256 + kg;
  const _Float16* a1 = Al + (size_t)(rowBase + lr) * 256 + kg;
  const _Float16* b0 = Bh + (size_t)(colBase + lr) * 256 + kg;
  f32x4 acc[2][4] = {};
  #pragma unroll
  for (int ks = 0; ks < 256; ks += 32) {
    f16x8 ah0 = *reinterpret_cast<const f16x8*>(a0 + ks);
    f16x8 ah1 = *reinterpret_cast<const f16x8*>(a0 + 16 * 256 + ks);
    f16x8 bh[4];
    #pragma unroll
    for (int cf = 0; cf < 4; ++cf)
      bh[cf] = *reinterpret_cast<const f16x8*>(b0 + cf * 16 * 256 + ks);
    #pragma unroll
    for (int cf = 0; cf < 4; ++cf) {
      acc[0][cf] = __builtin_amdgcn_mfma_f32_16x16x32_f16(ah0, bh[cf], acc[0][cf], 0, 0, 0);
      acc[1][cf] = __builtin_amdgcn_mfma_f32_16x16x32_f16(ah1, bh[cf], acc[1][cf], 0, 0, 0);
    }
    if (mat == 3) {  // wave-uniform: XR gets the A-lo correction pass
      f16x8 al0 = *reinterpret_cast<const f16x8*>(a1 + ks);
      f16x8 al1 = *reinterpret_cast<const f16x8*>(a1 + 16 * 256 + ks);
      #pragma unroll
      for (int cf = 0; cf < 4; ++cf) {
        acc[0][cf] = __builtin_amdgcn_mfma_f32_16x16x32_f16(al0, bh[cf], acc[0][cf], 0, 0, 0);
        acc[1][cf] = __builtin_amdgcn_mfma_f32_16x16x32_f16(al1, bh[cf], acc[1][cf], 0, 0, 0);
      }
    }
  }
  int rj = (lane >> 4) << 2;
  int colLoc = (wave << 6);
  #pragma unroll
  for (int rf = 0; rf < 2; ++rf) {
    #pragma unroll
    for (int cf = 0; cf < 4; ++cf) {
      int col = colLoc + cf * 16 + lr;
      float bb = bvec[(mat << 8) + col];
      #pragma unroll
      for (int j = 0; j < 4; ++j) {
        int row = rowBase + rf * 16 + rj + j;
        if (row < NN) {
          float val = acc[rf][cf][j] + bb;
          if (mat == 0)      Qf[(size_t)row * DIM + col] = val;
          else if (mat == 3) XRf[(size_t)row * DIM + col] = val;
          else KVh[(size_t)row * 512 + ((mat == 2) ? 256 : 0) + col] = (_Float16)val;
        }
      }
    }
  }
}

#define ATT_STEP(KK, VV, WW) do { \
    float part = q4.x * fmaf(WW, we4.x, (float)KK[0]) + q4.y * fmaf(WW, we4.y, (float)KK[1]) \
               + q4.z * fmaf(WW, we4.z, (float)KK[2]) + q4.w * fmaf(WW, we4.w, (float)KK[3]); \
    part += __shfl_xor(part, 1); \
    part += __shfl_xor(part, 2); \
    part += __shfl_xor(part, 4); \
    float alpha = part * 0.17677669529663687f; \
    float nm = fmaxf(m, alpha); \
    float sc = __expf(m - nm); \
    float pe = __expf(alpha - nm); \
    l = l * sc + pe; \
    a0 = fmaf(a0, sc, pe * fmaf(WW, we4.x, (float)VV[0])); \
    a1 = fmaf(a1, sc, pe * fmaf(WW, we4.y, (float)VV[1])); \
    a2 = fmaf(a2, sc, pe * fmaf(WW, we4.z, (float)VV[2])); \
    a3 = fmaf(a3, sc, pe * fmaf(WW, we4.w, (float)VV[3])); \
    m = nm; \
  } while (0)

// one wave per node; 64 lanes = 8 heads x 8 lanes x 4 dims; fused gate epilogue.
// K/V gathered as fp16 from packed KV rows (1 KB/node).
__global__ __launch_bounds__(256) void k_attn(
    const float* __restrict__ Qf, const _Float16* __restrict__ KVh,
    const float* __restrict__ XRf, const float* __restrict__ We,
    const float* __restrict__ Wb, const int* __restrict__ srcS,
    const float* __restrict__ wS, const int* __restrict__ offsets,
    _Float16* __restrict__ Ah, _Float16* __restrict__ Al,
    float* __restrict__ FinalOut) {
  int wid = (int)threadIdx.x >> 6, lane = (int)threadIdx.x & 63;
  int node = blockIdx.x * 4 + wid;
  if (node >= NN) return;
  int d0 = lane * 4;
  const float4 q4 = *reinterpret_cast<const float4*>(&Qf[(size_t)node * DIM + d0]);
  const float4 x4 = *reinterpret_cast<const float4*>(&XRf[(size_t)node * DIM + d0]);
  const float4 we4 = *reinterpret_cast<const float4*>(&We[d0]);
  const float4 wo = *reinterpret_cast<const float4*>(&Wb[d0]);
  const float4 wx = *reinterpret_cast<const float4*>(&Wb[DIM + d0]);
  const float4 wd = *reinterpret_cast<const float4*>(&Wb[2 * DIM + d0]);
  int beg = offsets[node], end = offsets[node + 1];
  beg = __builtin_amdgcn_readfirstlane(beg);
  end = __builtin_amdgcn_readfirstlane(end);
  float m = -INFINITY, l = 0.f, a0 = 0.f, a1 = 0.f, a2 = 0.f, a3 = 0.f;
  if (end > beg) {
    int pLast = end - 1;
    int sA = srcS[beg];
    float wA = wS[beg];
    int p1 = (beg + 1 <= pLast) ? beg + 1 : pLast;
    int sB = srcS[p1];
    float wB = wS[p1];
    const _Float16* rA = KVh + (size_t)sA * 512 + d0;
    const _Float16* rB = KVh + (size_t)sB * 512 + d0;
    f16x4 kA = *reinterpret_cast<const f16x4*>(rA);
    f16x4 vA = *reinterpret_cast<const f16x4*>(rA + 256);
    f16x4 kB = *reinterpret_cast<const f16x4*>(rB);
    f16x4 vB = *reinterpret_cast<const f16x4*>(rB + 256);
    int p = beg;
    #pragma unroll 2
    for (; p + 2 < end; ++p) {
      int sN = srcS[p + 2];
      float wN = wS[p + 2];
      const _Float16* rN = KVh + (size_t)sN * 512 + d0;
      f16x4 kN = *reinterpret_cast<const f16x4*>(rN);
      f16x4 vN = *reinterpret_cast<const f16x4*>(rN + 256);
      ATT_STEP(kA, vA, wA);
      kA = kB; vA = vB; wA = wB;
      kB = kN; vB = vN; wB = wN;
    }
    ATT_STEP(kA, vA, wA);
    if (p + 1 < end) ATT_STEP(kB, vB, wB);
  }
  float inv = 1.f / (l + 1e-16f);
  float o0 = a0 * inv, o1 = a1 * inv, o2 = a2 * inv, o3 = a3 * inv;
  float part = o0 * wo.x + o1 * wo.y + o2 * wo.z + o3 * wo.w
             + x4.x * wx.x + x4.y * wx.y + x4.z * wx.z + x4.w * wx.w
             + (o0 - x4.x) * wd.x + (o1 - x4.y) * wd.y
             + (o2 - x4.z) * wd.z + (o3 - x4.w) * wd.w;
  #pragma unroll
  for (int msk = 1; msk < 64; msk <<= 1) part += __shfl_xor(part, msk);
  float beta = 1.f / (1.f + __expf(-part));
  float h0 = beta * x4.x + (1.f - beta) * o0;
  float h1 = beta * x4.y + (1.f - beta) * o1;
  float h2 = beta * x4.z + (1.f - beta) * o2;
  float h3 = beta * x4.w + (1.f - beta) * o3;
  if (FinalOut) {
    float4 h; h.x = h0; h.y = h1; h.z = h2; h.w = h3;
    *reinterpret_cast<float4*>(&FinalOut[(size_t)node * DIM + d0]) = h;
  } else {
    f16x4 hh, ll;
    _Float16 t0 = (_Float16)h0, t1 = (_Float16)h1, t2 = (_Float16)h2, t3 = (_Float16)h3;
    hh[0] = t0; hh[1] = t1; hh[2] = t2; hh[3] = t3;
    ll[0] = (_Float16)(h0 - (float)t0); ll[1] = (_Float16)(h1 - (float)t1);
    ll[2] = (_Float16)(h2 - (float)t2); ll[3] = (_Float16)(h3 - (float)t3);
    *reinterpret_cast<f16x4*>(&Ah[(size_t)node * DIM + d0]) = hh;
    *reinterpret_cast<f16x4*>(&Al[(size_t)node * DIM + d0]) = ll;
  }
}

static inline size_t align256(size_t v) { return (v + 255) & ~(size_t)255; }

extern "C" void kernel_launch(void* const* d_in, const int* in_sizes, int n_in,
                              void* d_out, int out_size, void* d_ws, size_t ws_size,
                              hipStream_t stream) {
  const void* x = d_in[0];
  const int* eidx = (const int*)d_in[1];
  const void* ew = d_in[2];

  char* w = (char*)d_ws;
  size_t pos = 0;
  int* flags = (int*)(w + pos); pos = align256(pos + 2 * sizeof(int));
  float* Qf  = (float*)(w + pos); pos = align256(pos + (size_t)NROWS * DIM * 4);
  float* XRf = (float*)(w + pos); pos = align256(pos + (size_t)NROWS * DIM * 4);
  _Float16* KVh = (_Float16*)(w + pos); pos = align256(pos + (size_t)NROWS * 512 * 2);
  _Float16* Ah = (_Float16*)(w + pos); pos = align256(pos + (size_t)NROWS * DIM * 2);
  _Float16* Al = (_Float16*)(w + pos); pos = align256(pos + (size_t)NROWS * DIM * 2);
  _Float16* Bh = (_Float16*)(w + pos); pos = align256(pos + (size_t)8 * 65536 * 2);
  float* bvec = (float*)(w + pos);  pos = align256(pos + 2048 * 4);
  int* s32   = (int*)(w + pos);    pos = align256(pos + (size_t)EE * 4);
  int* d32   = (int*)(w + pos);    pos = align256(pos + (size_t)EE * 4);
  int* srcS  = (int*)(w + pos);    pos = align256(pos + (size_t)EE * 4);
  float* wS  = (float*)(w + pos);  pos = align256(pos + (size_t)EE * 4);
  int* counts  = (int*)(w + pos);  pos = align256(pos + (size_t)NN * 4);
  int* offsets = (int*)(w + pos);  pos = align256(pos + (size_t)(NN + 1) * 4);
  int* cursor  = (int*)(w + pos);  pos = align256(pos + (size_t)NN * 4);
  int* tmpoff  = (int*)(w + pos);  pos = align256(pos + (size_t)NN * 4);
  int* bsum    = (int*)(w + pos);  pos = align256(pos + 64 * 4);
  int* bbase   = (int*)(w + pos);  pos = align256(pos + 64 * 4);
  float* Pf    = (float*)(w + pos);

  PBatch pb;
  int off = 0;
  for (int i = 0; i < 20; ++i) {
    pb.src[i] = d_in[3 + i];
    pb.off[i] = off;
    off += in_sizes[3 + i];
  }
  pb.off[20] = off;

  k_detect<<<1, 64, 0, stream>>>((const unsigned int*)x, eidx, flags);
  hipMemsetAsync(counts, 0, (size_t)NN * 4, stream);
  k_idx_count<<<(EE + 255) / 256, 256, 0, stream>>>(eidx, s32, d32, counts, flags);
  k_scan1<<<SCANB, 256, 0, stream>>>(counts, tmpoff, bsum);
  k_scan2<<<1, 64, 0, stream>>>(bsum, bbase);
  k_scan3<<<SCANB, 256, 0, stream>>>(tmpoff, bbase, offsets, cursor);
  k_fill_sort<<<(EE + 255) / 256, 256, 0, stream>>>(d32, s32, ew, cursor, srcS, wS, flags);
  k_cvt_params<<<2064, 256, 0, stream>>>(pb, Pf, flags);

  const float* P[20];
  for (int i = 0; i < 20; ++i) P[i] = Pf + pb.off[i];

  WPtrs wp;
  BPtrs bp;
  for (int g = 0; g < 2; ++g) {
    const float* const* pp = &P[g * 10];
    wp.W[g * 4 + 0] = pp[0]; wp.W[g * 4 + 1] = pp[2];
    wp.W[g * 4 + 2] = pp[4]; wp.W[g * 4 + 3] = pp[7];
    bp.B[g * 4 + 0] = pp[1]; bp.B[g * 4 + 1] = pp[3];
    bp.B[g * 4 + 2] = pp[5]; bp.B[g * 4 + 3] = pp[8];
  }
  k_split_w<<<(8 * 65536 + 255) / 256, 256, 0, stream>>>(wp, Bh);
  k_bias<<<8, 256, 0, stream>>>(bp, bvec);
  k_split_x<<<(NROWS * DIM / 4 + 255) / 256, 256, 0, stream>>>(x, Ah, Al, flags);

  for (int layer = 0; layer < 3; ++layer) {
    int g = (layer == 0) ? 0 : 1;
    const float* const* pp = &P[g * 10];
    k_gemm_mfma<<<dim3(NROWS / 32, 4), 256, 0, stream>>>(
        Ah, Al, Bh + (size_t)g * 4 * 65536, bvec + g * 1024, Qf, KVh, XRf);
    k_attn<<<(NN + 3) / 4, 256, 0, stream>>>(Qf, KVh, XRf, pp[6], pp[9],
        srcS, wS, offsets, Ah, Al, (layer == 2) ? (float*)d_out : nullptr);
  }
}

// Round 8
// 308.390 us; speedup vs baseline: 2.6156x; 1.0741x over previous
//
#include <hip/hip_runtime.h>
#include <hip/hip_bf16.h>
#include <math.h>

#define NN 10000
#define EE 320000
#define DIM 256
#define NROWS 10016   // NN padded to 32
#define SCANB 40      // ceil(NN/256)

typedef __attribute__((ext_vector_type(8))) _Float16 f16x8;
typedef __attribute__((ext_vector_type(4))) _Float16 f16x4;
typedef __attribute__((ext_vector_type(4))) float f32x4;

__device__ __forceinline__ float bf2f(unsigned short u) {
  union { unsigned int ui; float f; } cv;
  cv.ui = ((unsigned int)u) << 16;
  return cv.f;
}

__device__ __forceinline__ float ldf(const void* p, int idx, int isf) {
  return isf ? ((const float*)p)[idx] : bf2f(((const unsigned short*)p)[idx]);
}

// block 0 wave 0: detect {f32 vs bf16} and {int64 vs int32}; all blocks: zero counts
__global__ __launch_bounds__(256) void k_detect_zero(const unsigned int* __restrict__ xw,
                                                     const int* __restrict__ ei,
                                                     int* __restrict__ flags,
                                                     int* __restrict__ counts) {
  int i = blockIdx.x * 256 + (int)threadIdx.x;
  if (i < NN) counts[i] = 0;
  if (blockIdx.x == 0 && threadIdx.x < 64) {
    int lane = threadIdx.x;
    int wild = 0;
    for (int t = 0; t < 16; ++t) {
      unsigned int w = xw[t * 64 + lane];
      unsigned int lo = w & 0xffffu;
      float f = bf2f((unsigned short)lo);
      float af = fabsf(f);
      if (lo != 0u && (af > 1e4f || af < 1e-30f)) wild++;
    }
    #pragma unroll
    for (int m = 1; m < 64; m <<= 1) wild += __shfl_xor(wild, m);
    int zeros = 0;
    for (int t = 0; t < 2; ++t) {
      if (ei[(t * 64 + lane) * 2 + 1] == 0) zeros++;
    }
    #pragma unroll
    for (int m = 1; m < 64; m <<= 1) zeros += __shfl_xor(zeros, m);
    if (lane == 0) {
      flags[0] = (wild > 100) ? 1 : 0;   // 1: floats f32
      flags[1] = (zeros > 100) ? 1 : 0;  // 1: indices int64
    }
  }
}

__global__ void k_idx_count(const int* __restrict__ ei, int* __restrict__ s32,
                            int* __restrict__ d32, int* __restrict__ counts,
                            const int* __restrict__ flags) {
  int i64 = flags[1];
  int i = blockIdx.x * blockDim.x + threadIdx.x;
  if (i < EE) {
    int s, d;
    if (i64) { s = ei[2 * i]; d = ei[2 * (EE + i)]; }
    else     { s = ei[i];     d = ei[EE + i]; }
    s32[i] = s; d32[i] = d;
    atomicAdd(&counts[d], 1);
  }
}

__global__ __launch_bounds__(256) void k_scan1(const int* __restrict__ counts,
                                               int* __restrict__ tmpoff,
                                               int* __restrict__ bsum) {
  __shared__ int s[256];
  int t = threadIdx.x;
  int i = blockIdx.x * 256 + t;
  int v = (i < NN) ? counts[i] : 0;
  s[t] = v;
  __syncthreads();
  for (int off = 1; off < 256; off <<= 1) {
    int x = (t >= off) ? s[t - off] : 0;
    __syncthreads();
    s[t] += x;
    __syncthreads();
  }
  if (i < NN) tmpoff[i] = s[t] - v;
  if (t == 255) bsum[blockIdx.x] = s[255];
}

// per block: base = sum(bsum[0..blockIdx-1]) via wave reduce; offsets = tmpoff + base
__global__ __launch_bounds__(256) void k_scan3(const int* __restrict__ tmpoff,
                                               const int* __restrict__ bsum,
                                               int* __restrict__ offsets,
                                               int* __restrict__ cursor) {
  __shared__ int sbase;
  if (threadIdx.x < 64) {
    int t = threadIdx.x;
    int v = (t < SCANB && t < (int)blockIdx.x) ? bsum[t] : 0;
    #pragma unroll
    for (int msk = 1; msk < 64; msk <<= 1) v += __shfl_xor(v, msk);
    if (t == 0) sbase = v;
  }
  __syncthreads();
  int base = sbase;
  int i = blockIdx.x * 256 + (int)threadIdx.x;
  if (i < NN) {
    int o = tmpoff[i] + base;
    offsets[i] = o;
    cursor[i] = o;
  }
  if (i == 0) offsets[NN] = EE;
}

__global__ void k_fill_sort(const int* __restrict__ d32, const int* __restrict__ s32,
                            const void* __restrict__ ew, int* __restrict__ cursor,
                            int2* __restrict__ eS, const int* __restrict__ flags) {
  int isf = flags[0];
  int i = blockIdx.x * blockDim.x + threadIdx.x;
  if (i < EE) {
    float wv = isf ? ((const float*)ew)[i] : bf2f(((const unsigned short*)ew)[i]);
    int p = atomicAdd(&cursor[d32[i]], 1);
    eS[p] = make_int2(s32[i], __float_as_int(wv));
  }
}

struct PackArgs {
  const void* W[8];    // 256x256 weight matrices
  const void* B8[8];   // 256 biases
  const void* WeWb[4]; // we1(256), wb1(768), we2(256), wb2(768)
  const void* x;
};

// fused param pack: W->Bh fp16 transposed; biases->bvec f32; We/Wb->f32; x->Ah/Al fp16 hi/lo
__global__ __launch_bounds__(256) void k_pack(PackArgs pa, _Float16* __restrict__ Bh,
                                              float* __restrict__ bvec,
                                              float* __restrict__ WeWbF,
                                              _Float16* __restrict__ Ah,
                                              _Float16* __restrict__ Al,
                                              const int* __restrict__ flags) {
  int isf = flags[0];
  int i = blockIdx.x * 256 + (int)threadIdx.x;
  if (i < 8 * 65536) {
    int m = i >> 16, col = (i >> 8) & 255, k = i & 255;
    Bh[i] = (_Float16)ldf(pa.W[m], k * 256 + col, isf);
    return;
  }
  i -= 8 * 65536;
  if (i < 2048) {
    bvec[i] = ldf(pa.B8[i >> 8], i & 255, isf);
    return;
  }
  i -= 2048;
  if (i < 2048) {
    int which, k;
    if (i < 256)       { which = 0; k = i; }
    else if (i < 1024) { which = 1; k = i - 256; }
    else if (i < 1280) { which = 2; k = i - 1024; }
    else               { which = 3; k = i - 1280; }
    WeWbF[i] = ldf(pa.WeWb[which], k, isf);
    return;
  }
  i -= 2048;
  // split_x: 4 elems per thread, rows NN..NROWS zero-padded
  if (i < NROWS * 64) {
    f16x4 h, l;
    if (i >= NN * 64) {
      h = (f16x4)(_Float16)0.f;
      l = (f16x4)(_Float16)0.f;
    } else {
      float v[4];
      if (isf) {
        float4 t = reinterpret_cast<const float4*>(pa.x)[i];
        v[0] = t.x; v[1] = t.y; v[2] = t.z; v[3] = t.w;
      } else {
        ushort4 t = reinterpret_cast<const ushort4*>(pa.x)[i];
        v[0] = bf2f(t.x); v[1] = bf2f(t.y); v[2] = bf2f(t.z); v[3] = bf2f(t.w);
      }
      #pragma unroll
      for (int j = 0; j < 4; ++j) {
        _Float16 hh = (_Float16)v[j];
        h[j] = hh;
        l[j] = (_Float16)(v[j] - (float)hh);
      }
    }
    reinterpret_cast<f16x4*>(Ah)[i] = h;
    reinterpret_cast<f16x4*>(Al)[i] = l;
  }
}

// fp16 MFMA GEMM. blockIdx.y = matrix: 0=Q(f32) 1=K(fp16) 2=V(fp16) 3=XR(f32, 2-pass)
__global__ __launch_bounds__(256, 4) void k_gemm_mfma(
    const _Float16* __restrict__ Ah, const _Float16* __restrict__ Al,
    const _Float16* __restrict__ Bh, const float* __restrict__ bvec,
    float* __restrict__ Qf, _Float16* __restrict__ KVh, float* __restrict__ XRf) {
  int tid = (int)threadIdx.x;
  int wave = tid >> 6, lane = tid & 63;
  int lr = lane & 15;
  int kg = (lane >> 4) << 3;
  int mat = blockIdx.y;
  int rowBase = blockIdx.x << 5;
  int colBase = (mat << 8) + (wave << 6);
  const _Float16* a0 = Ah + (size_t)(rowBase + lr) * 256 + kg;
  const _Float16* a1 = Al + (size_t)(rowBase + lr) * 256 + kg;
  const _Float16* b0 = Bh + (size_t)(colBase + lr) * 256 + kg;
  f32x4 acc[2][4] = {};
  #pragma unroll
  for (int ks = 0; ks < 256; ks += 32) {
    f16x8 ah0 = *reinterpret_cast<const f16x8*>(a0 + ks);
    f16x8 ah1 = *reinterpret_cast<const f16x8*>(a0 + 16 * 256 + ks);
    f16x8 bh[4];
    #pragma unroll
    for (int cf = 0; cf < 4; ++cf)
      bh[cf] = *reinterpret_cast<const f16x8*>(b0 + cf * 16 * 256 + ks);
    #pragma unroll
    for (int cf = 0; cf < 4; ++cf) {
      acc[0][cf] = __builtin_amdgcn_mfma_f32_16x16x32_f16(ah0, bh[cf], acc[0][cf], 0, 0, 0);
      acc[1][cf] = __builtin_amdgcn_mfma_f32_16x16x32_f16(ah1, bh[cf], acc[1][cf], 0, 0, 0);
    }
    if (mat == 3) {  // wave-uniform: XR gets the A-lo correction pass
      f16x8 al0 = *reinterpret_cast<const f16x8*>(a1 + ks);
      f16x8 al1 = *reinterpret_cast<const f16x8*>(a1 + 16 * 256 + ks);
      #pragma unroll
      for (int cf = 0; cf < 4; ++cf) {
        acc[0][cf] = __builtin_amdgcn_mfma_f32_16x16x32_f16(al0, bh[cf], acc[0][cf], 0, 0, 0);
        acc[1][cf] = __builtin_amdgcn_mfma_f32_16x16x32_f16(al1, bh[cf], acc[1][cf], 0, 0, 0);
      }
    }
  }
  int rj = (lane >> 4) << 2;
  int colLoc = (wave << 6);
  #pragma unroll
  for (int rf = 0; rf < 2; ++rf) {
    #pragma unroll
    for (int cf = 0; cf < 4; ++cf) {
      int col = colLoc + cf * 16 + lr;
      float bb = bvec[(mat << 8) + col];
      #pragma unroll
      for (int j = 0; j < 4; ++j) {
        int row = rowBase + rf * 16 + rj + j;
        if (row < NN) {
          float val = acc[rf][cf][j] + bb;
          if (mat == 0)      Qf[(size_t)row * DIM + col] = val;
          else if (mat == 3) XRf[(size_t)row * DIM + col] = val;
          else KVh[(size_t)row * 512 + ((mat == 2) ? 256 : 0) + col] = (_Float16)val;
        }
      }
    }
  }
}

#define ATT_STEP(KK, VV, WW) do { \
    float part = q4.x * fmaf(WW, we4.x, (float)KK[0]) + q4.y * fmaf(WW, we4.y, (float)KK[1]) \
               + q4.z * fmaf(WW, we4.z, (float)KK[2]) + q4.w * fmaf(WW, we4.w, (float)KK[3]); \
    part += __shfl_xor(part, 1); \
    part += __shfl_xor(part, 2); \
    part += __shfl_xor(part, 4); \
    float alpha = part * 0.17677669529663687f; \
    float nm = fmaxf(m, alpha); \
    float sc = __expf(m - nm); \
    float pe = __expf(alpha - nm); \
    l = fmaf(l, sc, pe); \
    a0 = fmaf(a0, sc, pe * fmaf(WW, we4.x, (float)VV[0])); \
    a1 = fmaf(a1, sc, pe * fmaf(WW, we4.y, (float)VV[1])); \
    a2 = fmaf(a2, sc, pe * fmaf(WW, we4.z, (float)VV[2])); \
    a3 = fmaf(a3, sc, pe * fmaf(WW, we4.w, (float)VV[3])); \
    m = nm; \
  } while (0)

// two edges per online-softmax update: independent dots, one max3, one rescale
#define PAIR_STEP(K0, V0, W0, K1, V1, W1) do { \
    float pt0 = q4.x * fmaf(W0, we4.x, (float)K0[0]) + q4.y * fmaf(W0, we4.y, (float)K0[1]) \
              + q4.z * fmaf(W0, we4.z, (float)K0[2]) + q4.w * fmaf(W0, we4.w, (float)K0[3]); \
    float pt1 = q4.x * fmaf(W1, we4.x, (float)K1[0]) + q4.y * fmaf(W1, we4.y, (float)K1[1]) \
              + q4.z * fmaf(W1, we4.z, (float)K1[2]) + q4.w * fmaf(W1, we4.w, (float)K1[3]); \
    pt0 += __shfl_xor(pt0, 1); pt1 += __shfl_xor(pt1, 1); \
    pt0 += __shfl_xor(pt0, 2); pt1 += __shfl_xor(pt1, 2); \
    pt0 += __shfl_xor(pt0, 4); pt1 += __shfl_xor(pt1, 4); \
    float al0 = pt0 * 0.17677669529663687f; \
    float al1 = pt1 * 0.17677669529663687f; \
    float nm = fmaxf(fmaxf(m, al0), al1); \
    float sc = __expf(m - nm); \
    float p0 = __expf(al0 - nm); \
    float p1 = __expf(al1 - nm); \
    l = fmaf(l, sc, p0 + p1); \
    a0 = fmaf(a0, sc, fmaf(p0, fmaf(W0, we4.x, (float)V0[0]), p1 * fmaf(W1, we4.x, (float)V1[0]))); \
    a1 = fmaf(a1, sc, fmaf(p0, fmaf(W0, we4.y, (float)V0[1]), p1 * fmaf(W1, we4.y, (float)V1[1]))); \
    a2 = fmaf(a2, sc, fmaf(p0, fmaf(W0, we4.z, (float)V0[2]), p1 * fmaf(W1, we4.z, (float)V1[2]))); \
    a3 = fmaf(a3, sc, fmaf(p0, fmaf(W0, we4.w, (float)V0[3]), p1 * fmaf(W1, we4.w, (float)V1[3]))); \
    m = nm; \
  } while (0)

// one wave per node; pair-batched online softmax, 3 pairs (6 edges) in flight.
__global__ __launch_bounds__(256) void k_attn(
    const float* __restrict__ Qf, const _Float16* __restrict__ KVh,
    const float* __restrict__ XRf, const float* __restrict__ We,
    const float* __restrict__ Wb, const int2* __restrict__ eS,
    const int* __restrict__ offsets, _Float16* __restrict__ Ah,
    _Float16* __restrict__ Al, float* __restrict__ FinalOut) {
  int wid = (int)threadIdx.x >> 6, lane = (int)threadIdx.x & 63;
  int node = blockIdx.x * 4 + wid;
  if (node >= NN) return;
  int d0 = lane * 4;
  const float4 q4 = *reinterpret_cast<const float4*>(&Qf[(size_t)node * DIM + d0]);
  const float4 x4 = *reinterpret_cast<const float4*>(&XRf[(size_t)node * DIM + d0]);
  const float4 we4 = *reinterpret_cast<const float4*>(&We[d0]);
  const float4 wo = *reinterpret_cast<const float4*>(&Wb[d0]);
  const float4 wx = *reinterpret_cast<const float4*>(&Wb[DIM + d0]);
  const float4 wd = *reinterpret_cast<const float4*>(&Wb[2 * DIM + d0]);
  int beg = offsets[node], end = offsets[node + 1];
  beg = __builtin_amdgcn_readfirstlane(beg);
  end = __builtin_amdgcn_readfirstlane(end);
  float m = -INFINITY, l = 0.f, a0 = 0.f, a1 = 0.f, a2 = 0.f, a3 = 0.f;
  int p = beg;
  if ((end - beg) & 1) {
    int2 e = eS[p];
    float w0 = __int_as_float(e.y);
    const _Float16* r = KVh + (size_t)e.x * 512 + d0;
    f16x4 k0 = *reinterpret_cast<const f16x4*>(r);
    f16x4 v0 = *reinterpret_cast<const f16x4*>(r + 256);
    ATT_STEP(k0, v0, w0);
    ++p;
  }
  if (p < end) {  // even remaining count >= 2
    int2 eA0 = eS[p], eA1 = eS[p + 1];
    int pb = (p + 3 < end) ? (p + 2) : p;
    int2 eB0 = eS[pb], eB1 = eS[pb + 1];
    const _Float16* rA0 = KVh + (size_t)eA0.x * 512 + d0;
    const _Float16* rA1 = KVh + (size_t)eA1.x * 512 + d0;
    const _Float16* rB0 = KVh + (size_t)eB0.x * 512 + d0;
    const _Float16* rB1 = KVh + (size_t)eB1.x * 512 + d0;
    f16x4 kA0 = *reinterpret_cast<const f16x4*>(rA0), vA0 = *reinterpret_cast<const f16x4*>(rA0 + 256);
    f16x4 kA1 = *reinterpret_cast<const f16x4*>(rA1), vA1 = *reinterpret_cast<const f16x4*>(rA1 + 256);
    f16x4 kB0 = *reinterpret_cast<const f16x4*>(rB0), vB0 = *reinterpret_cast<const f16x4*>(rB0 + 256);
    f16x4 kB1 = *reinterpret_cast<const f16x4*>(rB1), vB1 = *reinterpret_cast<const f16x4*>(rB1 + 256);
    float wA0 = __int_as_float(eA0.y), wA1 = __int_as_float(eA1.y);
    float wB0 = __int_as_float(eB0.y), wB1 = __int_as_float(eB1.y);
    #pragma unroll 2
    for (; p + 2 < end; p += 2) {
      int pc = (p + 5 < end) ? (p + 4) : p;
      int2 eC0 = eS[pc], eC1 = eS[pc + 1];
      const _Float16* rC0 = KVh + (size_t)eC0.x * 512 + d0;
      const _Float16* rC1 = KVh + (size_t)eC1.x * 512 + d0;
      f16x4 kC0 = *reinterpret_cast<const f16x4*>(rC0), vC0 = *reinterpret_cast<const f16x4*>(rC0 + 256);
      f16x4 kC1 = *reinterpret_cast<const f16x4*>(rC1), vC1 = *reinterpret_cast<const f16x4*>(rC1 + 256);
      float wC0 = __int_as_float(eC0.y), wC1 = __int_as_float(eC1.y);
      PAIR_STEP(kA0, vA0, wA0, kA1, vA1, wA1);
      kA0 = kB0; vA0 = vB0; wA0 = wB0; kA1 = kB1; vA1 = vB1; wA1 = wB1;
      kB0 = kC0; vB0 = vC0; wB0 = wC0; kB1 = kC1; vB1 = vC1; wB1 = wC1;
    }
    PAIR_STEP(kA0, vA0, wA0, kA1, vA1, wA1);
  }
  float inv = 1.f / (l + 1e-16f);
  float o0 = a0 * inv, o1 = a1 * inv, o2 = a2 * inv, o3 = a3 * inv;
  float part = o0 * wo.x + o1 * wo.y + o2 * wo.z + o3 * wo.w
             + x4.x * wx.x + x4.y * wx.y + x4.z * wx.z + x4.w * wx.w
             + (o0 - x4.x) * wd.x + (o1 - x4.y) * wd.y
             + (o2 - x4.z) * wd.z + (o3 - x4.w) * wd.w;
  #pragma unroll
  for (int msk = 1; msk < 64; msk <<= 1) part += __shfl_xor(part, msk);
  float beta = 1.f / (1.f + __expf(-part));
  float h0 = beta * x4.x + (1.f - beta) * o0;
  float h1 = beta * x4.y + (1.f - beta) * o1;
  float h2 = beta * x4.z + (1.f - beta) * o2;
  float h3 = beta * x4.w + (1.f - beta) * o3;
  if (FinalOut) {
    float4 h; h.x = h0; h.y = h1; h.z = h2; h.w = h3;
    *reinterpret_cast<float4*>(&FinalOut[(size_t)node * DIM + d0]) = h;
  } else {
    f16x4 hh, ll;
    _Float16 t0 = (_Float16)h0, t1 = (_Float16)h1, t2 = (_Float16)h2, t3 = (_Float16)h3;
    hh[0] = t0; hh[1] = t1; hh[2] = t2; hh[3] = t3;
    ll[0] = (_Float16)(h0 - (float)t0); ll[1] = (_Float16)(h1 - (float)t1);
    ll[2] = (_Float16)(h2 - (float)t2); ll[3] = (_Float16)(h3 - (float)t3);
    *reinterpret_cast<f16x4*>(&Ah[(size_t)node * DIM + d0]) = hh;
    *reinterpret_cast<f16x4*>(&Al[(size_t)node * DIM + d0]) = ll;
  }
}

static inline size_t align256(size_t v) { return (v + 255) & ~(size_t)255; }

extern "C" void kernel_launch(void* const* d_in, const int* in_sizes, int n_in,
                              void* d_out, int out_size, void* d_ws, size_t ws_size,
                              hipStream_t stream) {
  const void* x = d_in[0];
  const int* eidx = (const int*)d_in[1];
  const void* ew = d_in[2];

  char* w = (char*)d_ws;
  size_t pos = 0;
  int* flags = (int*)(w + pos); pos = align256(pos + 2 * sizeof(int));
  float* Qf  = (float*)(w + pos); pos = align256(pos + (size_t)NROWS * DIM * 4);
  float* XRf = (float*)(w + pos); pos = align256(pos + (size_t)NROWS * DIM * 4);
  _Float16* KVh = (_Float16*)(w + pos); pos = align256(pos + (size_t)NROWS * 512 * 2);
  _Float16* Ah = (_Float16*)(w + pos); pos = align256(pos + (size_t)NROWS * DIM * 2);
  _Float16* Al = (_Float16*)(w + pos); pos = align256(pos + (size_t)NROWS * DIM * 2);
  _Float16* Bh = (_Float16*)(w + pos); pos = align256(pos + (size_t)8 * 65536 * 2);
  float* bvec  = (float*)(w + pos); pos = align256(pos + 2048 * 4);
  float* WeWbF = (float*)(w + pos); pos = align256(pos + 2048 * 4);
  int* s32   = (int*)(w + pos);    pos = align256(pos + (size_t)EE * 4);
  int* d32   = (int*)(w + pos);    pos = align256(pos + (size_t)EE * 4);
  int2* eS   = (int2*)(w + pos);   pos = align256(pos + (size_t)EE * 8);
  int* counts  = (int*)(w + pos);  pos = align256(pos + (size_t)NN * 4);
  int* offsets = (int*)(w + pos);  pos = align256(pos + (size_t)(NN + 1) * 4);
  int* cursor  = (int*)(w + pos);  pos = align256(pos + (size_t)NN * 4);
  int* tmpoff  = (int*)(w + pos);  pos = align256(pos + (size_t)NN * 4);
  int* bsum    = (int*)(w + pos);  pos = align256(pos + 64 * 4);

  // params: d_in[3..22], order per group: Wq bq Wk bk Wv bv We Wskip bskip Wbeta
  PackArgs pa;
  pa.x = x;
  for (int g = 0; g < 2; ++g) {
    const void* const* pp = &d_in[3 + g * 10];
    pa.W[g * 4 + 0] = pp[0]; pa.W[g * 4 + 1] = pp[2];
    pa.W[g * 4 + 2] = pp[4]; pa.W[g * 4 + 3] = pp[7];
    pa.B8[g * 4 + 0] = pp[1]; pa.B8[g * 4 + 1] = pp[3];
    pa.B8[g * 4 + 2] = pp[5]; pa.B8[g * 4 + 3] = pp[8];
    pa.WeWb[g * 2 + 0] = pp[6];
    pa.WeWb[g * 2 + 1] = pp[9];
  }

  k_detect_zero<<<SCANB, 256, 0, stream>>>((const unsigned int*)x, eidx, flags, counts);
  k_pack<<<4568, 256, 0, stream>>>(pa, Bh, bvec, WeWbF, Ah, Al, flags);
  k_idx_count<<<(EE + 255) / 256, 256, 0, stream>>>(eidx, s32, d32, counts, flags);
  k_scan1<<<SCANB, 256, 0, stream>>>(counts, tmpoff, bsum);
  k_scan3<<<SCANB, 256, 0, stream>>>(tmpoff, bsum, offsets, cursor);
  k_fill_sort<<<(EE + 255) / 256, 256, 0, stream>>>(d32, s32, ew, cursor, eS, flags);

  for (int layer = 0; layer < 3; ++layer) {
    int g = (layer == 0) ? 0 : 1;
    k_gemm_mfma<<<dim3(NROWS / 32, 4), 256, 0, stream>>>(
        Ah, Al, Bh + (size_t)g * 4 * 65536, bvec + g * 1024, Qf, KVh, XRf);
    k_attn<<<(NN + 3) / 4, 256, 0, stream>>>(Qf, KVh, XRf,
        WeWbF + (g ? 1024 : 0), WeWbF + (g ? 1280 : 256),
        eS, offsets, Ah, Al, (layer == 2) ? (float*)d_out : nullptr);
  }
}

// Round 9
// 305.927 us; speedup vs baseline: 2.6366x; 1.0080x over previous
//
#include <hip/hip_runtime.h>
#include <hip/hip_bf16.h>
#include <math.h>

#define NN 10000
#define EE 320000
#define DIM 256
#define NROWS 10016   // NN padded to 32
#define SCANB 40      // ceil(NN/256)

typedef __attribute__((ext_vector_type(8))) _Float16 f16x8;
typedef __attribute__((ext_vector_type(4))) _Float16 f16x4;
typedef __attribute__((ext_vector_type(2))) _Float16 f16x2;
typedef __attribute__((ext_vector_type(4))) float f32x4;

#if defined(__has_builtin)
#if __has_builtin(__builtin_amdgcn_fdot2)
#define FDOT2(a, b, c) __builtin_amdgcn_fdot2(a, b, c, false)
#endif
#endif
#ifndef FDOT2
#define FDOT2(a, b, c) fmaf((float)a[0], (float)b[0], fmaf((float)a[1], (float)b[1], c))
#endif

__device__ __forceinline__ float bf2f(unsigned short u) {
  union { unsigned int ui; float f; } cv;
  cv.ui = ((unsigned int)u) << 16;
  return cv.f;
}

__device__ __forceinline__ float ldf(const void* p, int idx, int isf) {
  return isf ? ((const float*)p)[idx] : bf2f(((const unsigned short*)p)[idx]);
}

// block 0 wave 0: detect {f32 vs bf16} and {int64 vs int32}; all blocks: zero counts
__global__ __launch_bounds__(256) void k_detect_zero(const unsigned int* __restrict__ xw,
                                                     const int* __restrict__ ei,
                                                     int* __restrict__ flags,
                                                     int* __restrict__ counts) {
  int i = blockIdx.x * 256 + (int)threadIdx.x;
  if (i < NN) counts[i] = 0;
  if (blockIdx.x == 0 && threadIdx.x < 64) {
    int lane = threadIdx.x;
    int wild = 0;
    for (int t = 0; t < 16; ++t) {
      unsigned int w = xw[t * 64 + lane];
      unsigned int lo = w & 0xffffu;
      float f = bf2f((unsigned short)lo);
      float af = fabsf(f);
      if (lo != 0u && (af > 1e4f || af < 1e-30f)) wild++;
    }
    #pragma unroll
    for (int m = 1; m < 64; m <<= 1) wild += __shfl_xor(wild, m);
    int zeros = 0;
    for (int t = 0; t < 2; ++t) {
      if (ei[(t * 64 + lane) * 2 + 1] == 0) zeros++;
    }
    #pragma unroll
    for (int m = 1; m < 64; m <<= 1) zeros += __shfl_xor(zeros, m);
    if (lane == 0) {
      flags[0] = (wild > 100) ? 1 : 0;   // 1: floats f32
      flags[1] = (zeros > 100) ? 1 : 0;  // 1: indices int64
    }
  }
}

__global__ void k_idx_count(const int* __restrict__ ei, int* __restrict__ s32,
                            int* __restrict__ d32, int* __restrict__ counts,
                            const int* __restrict__ flags) {
  int i64 = flags[1];
  int i = blockIdx.x * blockDim.x + threadIdx.x;
  if (i < EE) {
    int s, d;
    if (i64) { s = ei[2 * i]; d = ei[2 * (EE + i)]; }
    else     { s = ei[i];     d = ei[EE + i]; }
    s32[i] = s; d32[i] = d;
    atomicAdd(&counts[d], 1);
  }
}

__global__ __launch_bounds__(256) void k_scan1(const int* __restrict__ counts,
                                               int* __restrict__ tmpoff,
                                               int* __restrict__ bsum) {
  __shared__ int s[256];
  int t = threadIdx.x;
  int i = blockIdx.x * 256 + t;
  int v = (i < NN) ? counts[i] : 0;
  s[t] = v;
  __syncthreads();
  for (int off = 1; off < 256; off <<= 1) {
    int x = (t >= off) ? s[t - off] : 0;
    __syncthreads();
    s[t] += x;
    __syncthreads();
  }
  if (i < NN) tmpoff[i] = s[t] - v;
  if (t == 255) bsum[blockIdx.x] = s[255];
}

// per block: base = sum(bsum[0..blockIdx-1]) via wave reduce; offsets = tmpoff + base
__global__ __launch_bounds__(256) void k_scan3(const int* __restrict__ tmpoff,
                                               const int* __restrict__ bsum,
                                               int* __restrict__ offsets,
                                               int* __restrict__ cursor) {
  __shared__ int sbase;
  if (threadIdx.x < 64) {
    int t = threadIdx.x;
    int v = (t < SCANB && t < (int)blockIdx.x) ? bsum[t] : 0;
    #pragma unroll
    for (int msk = 1; msk < 64; msk <<= 1) v += __shfl_xor(v, msk);
    if (t == 0) sbase = v;
  }
  __syncthreads();
  int base = sbase;
  int i = blockIdx.x * 256 + (int)threadIdx.x;
  if (i < NN) {
    int o = tmpoff[i] + base;
    offsets[i] = o;
    cursor[i] = o;
  }
  if (i == 0) offsets[NN] = EE;
}

__global__ void k_fill_sort(const int* __restrict__ d32, const int* __restrict__ s32,
                            const void* __restrict__ ew, int* __restrict__ cursor,
                            int2* __restrict__ eS, const int* __restrict__ flags) {
  int isf = flags[0];
  int i = blockIdx.x * blockDim.x + threadIdx.x;
  if (i < EE) {
    float wv = isf ? ((const float*)ew)[i] : bf2f(((const unsigned short*)ew)[i]);
    int p = atomicAdd(&cursor[d32[i]], 1);
    eS[p] = make_int2(s32[i], __float_as_int(wv));
  }
}

struct PackArgs {
  const void* W[8];    // 256x256 weight matrices
  const void* B8[8];   // 256 biases
  const void* WeWb[4]; // we1(256), wb1(768), we2(256), wb2(768)
  const void* x;
};

// fused param pack: W->Bh fp16 transposed; biases->bvec f32; We/Wb->f32; x->Ah/Al fp16 hi/lo
__global__ __launch_bounds__(256) void k_pack(PackArgs pa, _Float16* __restrict__ Bh,
                                              float* __restrict__ bvec,
                                              float* __restrict__ WeWbF,
                                              _Float16* __restrict__ Ah,
                                              _Float16* __restrict__ Al,
                                              const int* __restrict__ flags) {
  int isf = flags[0];
  int i = blockIdx.x * 256 + (int)threadIdx.x;
  if (i < 8 * 65536) {
    int m = i >> 16, col = (i >> 8) & 255, k = i & 255;
    Bh[i] = (_Float16)ldf(pa.W[m], k * 256 + col, isf);
    return;
  }
  i -= 8 * 65536;
  if (i < 2048) {
    bvec[i] = ldf(pa.B8[i >> 8], i & 255, isf);
    return;
  }
  i -= 2048;
  if (i < 2048) {
    int which, k;
    if (i < 256)       { which = 0; k = i; }
    else if (i < 1024) { which = 1; k = i - 256; }
    else if (i < 1280) { which = 2; k = i - 1024; }
    else               { which = 3; k = i - 1280; }
    WeWbF[i] = ldf(pa.WeWb[which], k, isf);
    return;
  }
  i -= 2048;
  // split_x: 4 elems per thread, rows NN..NROWS zero-padded
  if (i < NROWS * 64) {
    f16x4 h, l;
    if (i >= NN * 64) {
      h = (f16x4)(_Float16)0.f;
      l = (f16x4)(_Float16)0.f;
    } else {
      float v[4];
      if (isf) {
        float4 t = reinterpret_cast<const float4*>(pa.x)[i];
        v[0] = t.x; v[1] = t.y; v[2] = t.z; v[3] = t.w;
      } else {
        ushort4 t = reinterpret_cast<const ushort4*>(pa.x)[i];
        v[0] = bf2f(t.x); v[1] = bf2f(t.y); v[2] = bf2f(t.z); v[3] = bf2f(t.w);
      }
      #pragma unroll
      for (int j = 0; j < 4; ++j) {
        _Float16 hh = (_Float16)v[j];
        h[j] = hh;
        l[j] = (_Float16)(v[j] - (float)hh);
      }
    }
    reinterpret_cast<f16x4*>(Ah)[i] = h;
    reinterpret_cast<f16x4*>(Al)[i] = l;
  }
}

// fp16 MFMA GEMM. blockIdx.y = matrix: 0=Q(f32) 1=K(fp16) 2=V(fp16) 3=XR(f32, 2-pass)
__global__ __launch_bounds__(256, 4) void k_gemm_mfma(
    const _Float16* __restrict__ Ah, const _Float16* __restrict__ Al,
    const _Float16* __restrict__ Bh, const float* __restrict__ bvec,
    float* __restrict__ Qf, _Float16* __restrict__ KVh, float* __restrict__ XRf) {
  int tid = (int)threadIdx.x;
  int wave = tid >> 6, lane = tid & 63;
  int lr = lane & 15;
  int kg = (lane >> 4) << 3;
  int mat = blockIdx.y;
  int rowBase = blockIdx.x << 5;
  int colBase = (mat << 8) + (wave << 6);
  const _Float16* a0 = Ah + (size_t)(rowBase + lr) * 256 + kg;
  const _Float16* a1 = Al + (size_t)(rowBase + lr) * 256 + kg;
  const _Float16* b0 = Bh + (size_t)(colBase + lr) * 256 + kg;
  f32x4 acc[2][4] = {};
  #pragma unroll
  for (int ks = 0; ks < 256; ks += 32) {
    f16x8 ah0 = *reinterpret_cast<const f16x8*>(a0 + ks);
    f16x8 ah1 = *reinterpret_cast<const f16x8*>(a0 + 16 * 256 + ks);
    f16x8 bh[4];
    #pragma unroll
    for (int cf = 0; cf < 4; ++cf)
      bh[cf] = *reinterpret_cast<const f16x8*>(b0 + cf * 16 * 256 + ks);
    #pragma unroll
    for (int cf = 0; cf < 4; ++cf) {
      acc[0][cf] = __builtin_amdgcn_mfma_f32_16x16x32_f16(ah0, bh[cf], acc[0][cf], 0, 0, 0);
      acc[1][cf] = __builtin_amdgcn_mfma_f32_16x16x32_f16(ah1, bh[cf], acc[1][cf], 0, 0, 0);
    }
    if (mat == 3) {  // wave-uniform: XR gets the A-lo correction pass
      f16x8 al0 = *reinterpret_cast<const f16x8*>(a1 + ks);
      f16x8 al1 = *reinterpret_cast<const f16x8*>(a1 + 16 * 256 + ks);
      #pragma unroll
      for (int cf = 0; cf < 4; ++cf) {
        acc[0][cf] = __builtin_amdgcn_mfma_f32_16x16x32_f16(al0, bh[cf], acc[0][cf], 0, 0, 0);
        acc[1][cf] = __builtin_amdgcn_mfma_f32_16x16x32_f16(al1, bh[cf], acc[1][cf], 0, 0, 0);
      }
    }
  }
  int rj = (lane >> 4) << 2;
  int colLoc = (wave << 6);
  #pragma unroll
  for (int rf = 0; rf < 2; ++rf) {
    #pragma unroll
    for (int cf = 0; cf < 4; ++cf) {
      int col = colLoc + cf * 16 + lr;
      float bb = bvec[(mat << 8) + col];
      #pragma unroll
      for (int j = 0; j < 4; ++j) {
        int row = rowBase + rf * 16 + rj + j;
        if (row < NN) {
          float val = acc[rf][cf][j] + bb;
          if (mat == 0)      Qf[(size_t)row * DIM + col] = val;
          else if (mat == 3) XRf[(size_t)row * DIM + col] = val;
          else KVh[(size_t)row * 512 + ((mat == 2) ? 256 : 0) + col] = (_Float16)val;
        }
      }
    }
  }
}

// single-edge online-softmax step (qwe/sw form)
#define ATT_STEP(KK, VV, WW) do { \
    f16x2 kka = {KK[0], KK[1]}, kkb = {KK[2], KK[3]}; \
    float pt = FDOT2(kka, qha, FDOT2(kkb, qhb, 0.f)); \
    pt += __shfl_xor(pt, 1); \
    pt += __shfl_xor(pt, 2); \
    pt += __shfl_xor(pt, 4); \
    float alpha = fmaf(WW, qwe, pt) * 0.17677669529663687f; \
    float nm = fmaxf(m, alpha); \
    float sc = __expf(m - nm); \
    float pe = __expf(alpha - nm); \
    l = fmaf(l, sc, pe); \
    sw = fmaf(sw, sc, pe * WW); \
    a0 = fmaf(a0, sc, pe * (float)VV[0]); \
    a1 = fmaf(a1, sc, pe * (float)VV[1]); \
    a2 = fmaf(a2, sc, pe * (float)VV[2]); \
    a3 = fmaf(a3, sc, pe * (float)VV[3]); \
    m = nm; \
  } while (0)

// two edges per update: independent packed dots, one max3, one rescale
#define PAIR_STEP(K0, V0, W0, K1, V1, W1) do { \
    f16x2 k0a = {K0[0], K0[1]}, k0b = {K0[2], K0[3]}; \
    f16x2 k1a = {K1[0], K1[1]}, k1b = {K1[2], K1[3]}; \
    float pt0 = FDOT2(k0a, qha, FDOT2(k0b, qhb, 0.f)); \
    float pt1 = FDOT2(k1a, qha, FDOT2(k1b, qhb, 0.f)); \
    pt0 += __shfl_xor(pt0, 1); pt1 += __shfl_xor(pt1, 1); \
    pt0 += __shfl_xor(pt0, 2); pt1 += __shfl_xor(pt1, 2); \
    pt0 += __shfl_xor(pt0, 4); pt1 += __shfl_xor(pt1, 4); \
    float al0 = fmaf(W0, qwe, pt0) * 0.17677669529663687f; \
    float al1 = fmaf(W1, qwe, pt1) * 0.17677669529663687f; \
    float nm = fmaxf(fmaxf(m, al0), al1); \
    float sc = __expf(m - nm); \
    float p0 = __expf(al0 - nm); \
    float p1 = __expf(al1 - nm); \
    l = fmaf(l, sc, p0 + p1); \
    sw = fmaf(sw, sc, fmaf(p0, W0, p1 * W1)); \
    a0 = fmaf(a0, sc, fmaf(p0, (float)V0[0], p1 * (float)V1[0])); \
    a1 = fmaf(a1, sc, fmaf(p0, (float)V0[1], p1 * (float)V1[1])); \
    a2 = fmaf(a2, sc, fmaf(p0, (float)V0[2], p1 * (float)V1[2])); \
    a3 = fmaf(a3, sc, fmaf(p0, (float)V0[3], p1 * (float)V1[3])); \
    m = nm; \
  } while (0)

// one wave per node; pair-batched online softmax with algebraic We elimination:
// alpha = (q.k + w*(q.we))/sqrt(d); out = (sum pe*v + (sum pe*w)*we)/l
__global__ __launch_bounds__(256) void k_attn(
    const float* __restrict__ Qf, const _Float16* __restrict__ KVh,
    const float* __restrict__ XRf, const float* __restrict__ We,
    const float* __restrict__ Wb, const int2* __restrict__ eS,
    const int* __restrict__ offsets, _Float16* __restrict__ Ah,
    _Float16* __restrict__ Al, float* __restrict__ FinalOut) {
  int wid = (int)threadIdx.x >> 6, lane = (int)threadIdx.x & 63;
  int node = blockIdx.x * 4 + wid;
  if (node >= NN) return;
  int d0 = lane * 4;
  const float4 q4 = *reinterpret_cast<const float4*>(&Qf[(size_t)node * DIM + d0]);
  const float4 x4 = *reinterpret_cast<const float4*>(&XRf[(size_t)node * DIM + d0]);
  const float4 we4 = *reinterpret_cast<const float4*>(&We[d0]);
  const float4 wo = *reinterpret_cast<const float4*>(&Wb[d0]);
  const float4 wx = *reinterpret_cast<const float4*>(&Wb[DIM + d0]);
  const float4 wd = *reinterpret_cast<const float4*>(&Wb[2 * DIM + d0]);
  f16x2 qha = {(_Float16)q4.x, (_Float16)q4.y};
  f16x2 qhb = {(_Float16)q4.z, (_Float16)q4.w};
  // qwe = q . we per head (uniform across the head's 8 lanes after reduce)
  float qwe = q4.x * we4.x + q4.y * we4.y + q4.z * we4.z + q4.w * we4.w;
  qwe += __shfl_xor(qwe, 1);
  qwe += __shfl_xor(qwe, 2);
  qwe += __shfl_xor(qwe, 4);
  int beg = offsets[node], end = offsets[node + 1];
  beg = __builtin_amdgcn_readfirstlane(beg);
  end = __builtin_amdgcn_readfirstlane(end);
  float m = -INFINITY, l = 0.f, sw = 0.f, a0 = 0.f, a1 = 0.f, a2 = 0.f, a3 = 0.f;
  int p = beg;
  if ((end - beg) & 1) {
    int2 e = eS[p];
    float w0 = __int_as_float(e.y);
    const _Float16* r = KVh + (size_t)e.x * 512 + d0;
    f16x4 k0 = *reinterpret_cast<const f16x4*>(r);
    f16x4 v0 = *reinterpret_cast<const f16x4*>(r + 256);
    ATT_STEP(k0, v0, w0);
    ++p;
  }
  if (p < end) {  // even remaining count >= 2
    int2 eA0 = eS[p], eA1 = eS[p + 1];
    int pb = (p + 3 < end) ? (p + 2) : p;
    int2 eB0 = eS[pb], eB1 = eS[pb + 1];
    const _Float16* rA0 = KVh + (size_t)eA0.x * 512 + d0;
    const _Float16* rA1 = KVh + (size_t)eA1.x * 512 + d0;
    const _Float16* rB0 = KVh + (size_t)eB0.x * 512 + d0;
    const _Float16* rB1 = KVh + (size_t)eB1.x * 512 + d0;
    f16x4 kA0 = *reinterpret_cast<const f16x4*>(rA0), vA0 = *reinterpret_cast<const f16x4*>(rA0 + 256);
    f16x4 kA1 = *reinterpret_cast<const f16x4*>(rA1), vA1 = *reinterpret_cast<const f16x4*>(rA1 + 256);
    f16x4 kB0 = *reinterpret_cast<const f16x4*>(rB0), vB0 = *reinterpret_cast<const f16x4*>(rB0 + 256);
    f16x4 kB1 = *reinterpret_cast<const f16x4*>(rB1), vB1 = *reinterpret_cast<const f16x4*>(rB1 + 256);
    float wA0 = __int_as_float(eA0.y), wA1 = __int_as_float(eA1.y);
    float wB0 = __int_as_float(eB0.y), wB1 = __int_as_float(eB1.y);
    #pragma unroll 2
    for (; p + 2 < end; p += 2) {
      int pc = (p + 5 < end) ? (p + 4) : p;
      int2 eC0 = eS[pc], eC1 = eS[pc + 1];
      const _Float16* rC0 = KVh + (size_t)eC0.x * 512 + d0;
      const _Float16* rC1 = KVh + (size_t)eC1.x * 512 + d0;
      f16x4 kC0 = *reinterpret_cast<const f16x4*>(rC0), vC0 = *reinterpret_cast<const f16x4*>(rC0 + 256);
      f16x4 kC1 = *reinterpret_cast<const f16x4*>(rC1), vC1 = *reinterpret_cast<const f16x4*>(rC1 + 256);
      float wC0 = __int_as_float(eC0.y), wC1 = __int_as_float(eC1.y);
      PAIR_STEP(kA0, vA0, wA0, kA1, vA1, wA1);
      kA0 = kB0; vA0 = vB0; wA0 = wB0; kA1 = kB1; vA1 = vB1; wA1 = wB1;
      kB0 = kC0; vB0 = vC0; wB0 = wC0; kB1 = kC1; vB1 = vC1; wB1 = wC1;
    }
    PAIR_STEP(kA0, vA0, wA0, kA1, vA1, wA1);
  }
  float inv = 1.f / (l + 1e-16f);
  float o0 = fmaf(sw, we4.x, a0) * inv;
  float o1 = fmaf(sw, we4.y, a1) * inv;
  float o2 = fmaf(sw, we4.z, a2) * inv;
  float o3 = fmaf(sw, we4.w, a3) * inv;
  float part = o0 * wo.x + o1 * wo.y + o2 * wo.z + o3 * wo.w
             + x4.x * wx.x + x4.y * wx.y + x4.z * wx.z + x4.w * wx.w
             + (o0 - x4.x) * wd.x + (o1 - x4.y) * wd.y
             + (o2 - x4.z) * wd.z + (o3 - x4.w) * wd.w;
  #pragma unroll
  for (int msk = 1; msk < 64; msk <<= 1) part += __shfl_xor(part, msk);
  float beta = 1.f / (1.f + __expf(-part));
  float h0 = beta * x4.x + (1.f - beta) * o0;
  float h1 = beta * x4.y + (1.f - beta) * o1;
  float h2 = beta * x4.z + (1.f - beta) * o2;
  float h3 = beta * x4.w + (1.f - beta) * o3;
  if (FinalOut) {
    float4 h; h.x = h0; h.y = h1; h.z = h2; h.w = h3;
    *reinterpret_cast<float4*>(&FinalOut[(size_t)node * DIM + d0]) = h;
  } else {
    f16x4 hh, ll;
    _Float16 t0 = (_Float16)h0, t1 = (_Float16)h1, t2 = (_Float16)h2, t3 = (_Float16)h3;
    hh[0] = t0; hh[1] = t1; hh[2] = t2; hh[3] = t3;
    ll[0] = (_Float16)(h0 - (float)t0); ll[1] = (_Float16)(h1 - (float)t1);
    ll[2] = (_Float16)(h2 - (float)t2); ll[3] = (_Float16)(h3 - (float)t3);
    *reinterpret_cast<f16x4*>(&Ah[(size_t)node * DIM + d0]) = hh;
    *reinterpret_cast<f16x4*>(&Al[(size_t)node * DIM + d0]) = ll;
  }
}

static inline size_t align256(size_t v) { return (v + 255) & ~(size_t)255; }

extern "C" void kernel_launch(void* const* d_in, const int* in_sizes, int n_in,
                              void* d_out, int out_size, void* d_ws, size_t ws_size,
                              hipStream_t stream) {
  const void* x = d_in[0];
  const int* eidx = (const int*)d_in[1];
  const void* ew = d_in[2];

  char* w = (char*)d_ws;
  size_t pos = 0;
  int* flags = (int*)(w + pos); pos = align256(pos + 2 * sizeof(int));
  float* Qf  = (float*)(w + pos); pos = align256(pos + (size_t)NROWS * DIM * 4);
  float* XRf = (float*)(w + pos); pos = align256(pos + (size_t)NROWS * DIM * 4);
  _Float16* KVh = (_Float16*)(w + pos); pos = align256(pos + (size_t)NROWS * 512 * 2);
  _Float16* Ah = (_Float16*)(w + pos); pos = align256(pos + (size_t)NROWS * DIM * 2);
  _Float16* Al = (_Float16*)(w + pos); pos = align256(pos + (size_t)NROWS * DIM * 2);
  _Float16* Bh = (_Float16*)(w + pos); pos = align256(pos + (size_t)8 * 65536 * 2);
  float* bvec  = (float*)(w + pos); pos = align256(pos + 2048 * 4);
  float* WeWbF = (float*)(w + pos); pos = align256(pos + 2048 * 4);
  int* s32   = (int*)(w + pos);    pos = align256(pos + (size_t)EE * 4);
  int* d32   = (int*)(w + pos);    pos = align256(pos + (size_t)EE * 4);
  int2* eS   = (int2*)(w + pos);   pos = align256(pos + (size_t)EE * 8);
  int* counts  = (int*)(w + pos);  pos = align256(pos + (size_t)NN * 4);
  int* offsets = (int*)(w + pos);  pos = align256(pos + (size_t)(NN + 1) * 4);
  int* cursor  = (int*)(w + pos);  pos = align256(pos + (size_t)NN * 4);
  int* tmpoff  = (int*)(w + pos);  pos = align256(pos + (size_t)NN * 4);
  int* bsum    = (int*)(w + pos);  pos = align256(pos + 64 * 4);

  // params: d_in[3..22], order per group: Wq bq Wk bk Wv bv We Wskip bskip Wbeta
  PackArgs pa;
  pa.x = x;
  for (int g = 0; g < 2; ++g) {
    const void* const* pp = &d_in[3 + g * 10];
    pa.W[g * 4 + 0] = pp[0]; pa.W[g * 4 + 1] = pp[2];
    pa.W[g * 4 + 2] = pp[4]; pa.W[g * 4 + 3] = pp[7];
    pa.B8[g * 4 + 0] = pp[1]; pa.B8[g * 4 + 1] = pp[3];
    pa.B8[g * 4 + 2] = pp[5]; pa.B8[g * 4 + 3] = pp[8];
    pa.WeWb[g * 2 + 0] = pp[6];
    pa.WeWb[g * 2 + 1] = pp[9];
  }

  k_detect_zero<<<SCANB, 256, 0, stream>>>((const unsigned int*)x, eidx, flags, counts);
  k_pack<<<4568, 256, 0, stream>>>(pa, Bh, bvec, WeWbF, Ah, Al, flags);
  k_idx_count<<<(EE + 255) / 256, 256, 0, stream>>>(eidx, s32, d32, counts, flags);
  k_scan1<<<SCANB, 256, 0, stream>>>(counts, tmpoff, bsum);
  k_scan3<<<SCANB, 256, 0, stream>>>(tmpoff, bsum, offsets, cursor);
  k_fill_sort<<<(EE + 255) / 256, 256, 0, stream>>>(d32, s32, ew, cursor, eS, flags);

  for (int layer = 0; layer < 3; ++layer) {
    int g = (layer == 0) ? 0 : 1;
    k_gemm_mfma<<<dim3(NROWS / 32, 4), 256, 0, stream>>>(
        Ah, Al, Bh + (size_t)g * 4 * 65536, bvec + g * 1024, Qf, KVh, XRf);
    k_attn<<<(NN + 3) / 4, 256, 0, stream>>>(Qf, KVh, XRf,
        WeWbF + (g ? 1024 : 0), WeWbF + (g ? 1280 : 256),
        eS, offsets, Ah, Al, (layer == 2) ? (float*)d_out : nullptr);
  }
}